// Round 1
// baseline (324.034 us; speedup 1.0000x reference)
//
#include <hip/hip_runtime.h>
#include <stdint.h>

// ---------------------------------------------------------------------------
// MultiheadAttention fused pipeline, bf16 MFMA compute:
//   cast(x,ipw,opw) -> bf16 ; rope tables
//   gemm1: qkv = x @ ipw^T + ipb                  (bf16 out, [8192,3072])
//   rope_reshape: Q*0.125,K roped -> [B,H,T,64]; V reshaped
//   attn: causal flash attention (64-row q blocks, 64 kv tiles)
//   gemm2: out = y @ opw^T + opb                  (fp32 out)
// B=8 T=1024 C=1024 H=16 hd=64
// ---------------------------------------------------------------------------

typedef __bf16 bf16x8 __attribute__((ext_vector_type(8)));
typedef float f32x4 __attribute__((ext_vector_type(4)));
typedef __attribute__((address_space(1))) unsigned int as1_u32;
typedef __attribute__((address_space(3))) unsigned int as3_u32;

#define MFMA16(a, b, c) __builtin_amdgcn_mfma_f32_16x16x32_bf16((a), (b), (c), 0, 0, 0)

static __device__ __forceinline__ unsigned short f2bf(float f) {
    union { float f; unsigned u; } x; x.f = f;
    return (unsigned short)((x.u + 0x7fffu + ((x.u >> 16) & 1u)) >> 16);
}
static __device__ __forceinline__ float bf2f(unsigned short u) {
    union { unsigned u; float f; } x; x.u = ((unsigned)u) << 16;
    return x.f;
}
static __device__ __forceinline__ bf16x8 ld_bf16x8(const void* p) {
    return *(const bf16x8*)p;
}

// ---------------- fp32 -> bf16 cast, 8 elems/thread ----------------
__global__ void cast_f32_bf16(const float* __restrict__ in,
                              unsigned short* __restrict__ out, int n8) {
    int i = blockIdx.x * blockDim.x + threadIdx.x;
    if (i >= n8) return;
    float4 a = ((const float4*)in)[2 * i];
    float4 b = ((const float4*)in)[2 * i + 1];
    union { unsigned short us[8]; uint4 v; } o;
    o.us[0] = f2bf(a.x); o.us[1] = f2bf(a.y); o.us[2] = f2bf(a.z); o.us[3] = f2bf(a.w);
    o.us[4] = f2bf(b.x); o.us[5] = f2bf(b.y); o.us[6] = f2bf(b.z); o.us[7] = f2bf(b.w);
    ((uint4*)out)[i] = o.v;
}

// ---------------- RoPE cos/sin tables [1024][32] fp32 ----------------
__global__ void rope_table(float* __restrict__ ct, float* __restrict__ st) {
    int idx = blockIdx.x * blockDim.x + threadIdx.x;
    if (idx >= 1024 * 32) return;
    int t = idx >> 5, i = idx & 31;
    float inv = powf(10000.0f, -(float)(2 * i) * (1.0f / 64.0f));
    float f = (float)t * inv;
    ct[idx] = cosf(f);
    st[idx] = sinf(f);
}

// ---------------- bf16 GEMM: C[m,n] = sum_k A[m,k]*W[n,k] + bias[n] --------
// m97 structure: BM=BN=128, BK=32, 256 thr (4 waves 2x2, 64x64 each),
// global_load_lds dwordx4 staging, 2 barriers per K step.
template <int NC, bool OUT_BF16>
__global__ __launch_bounds__(256) void gemm_bt(const unsigned short* __restrict__ A,
                                               const unsigned short* __restrict__ W,
                                               const float* __restrict__ bias,
                                               void* __restrict__ Cout, int K) {
    __shared__ __attribute__((aligned(16))) unsigned short As[128 * 32];
    __shared__ __attribute__((aligned(16))) unsigned short Bs[128 * 32];

    constexpr int NT = NC / 128;
    int nwg = gridDim.x;
    int bid = blockIdx.x;
    int lg = (bid & 7) * (nwg >> 3) + (bid >> 3);  // XCD swizzle (nwg % 8 == 0)
    int tm = lg / NT, tn = lg % NT;
    int m0 = tm * 128, n0 = tn * 128;

    int tid = threadIdx.x;
    int w = tid >> 6, l = tid & 63;
    int lr = l & 15, g = l >> 4;
    int ldsb = __builtin_amdgcn_readfirstlane(w * 512);  // ushort offset, wave-uniform

    // staging chunks: chunk c -> row c>>2, 16B slot c&3 (row-major [128][32] bf16)
    int c0 = tid, c1 = tid + 256;
    const unsigned short* A0 = A + (size_t)(m0 + (c0 >> 2)) * K + (c0 & 3) * 8;
    const unsigned short* A1 = A + (size_t)(m0 + (c1 >> 2)) * K + (c1 & 3) * 8;
    const unsigned short* W0 = W + (size_t)(n0 + (c0 >> 2)) * K + (c0 & 3) * 8;
    const unsigned short* W1 = W + (size_t)(n0 + (c1 >> 2)) * K + (c1 & 3) * 8;

    f32x4 acc[4][4] = {};
    int wr = (w >> 1) * 64, wc = (w & 1) * 64;

    for (int k0 = 0; k0 < K; k0 += 32) {
        __syncthreads();  // previous tile consumed
        __builtin_amdgcn_global_load_lds((const as1_u32*)(A0 + k0), (as3_u32*)(As + ldsb), 16, 0, 0);
        __builtin_amdgcn_global_load_lds((const as1_u32*)(A1 + k0), (as3_u32*)(As + 2048 + ldsb), 16, 0, 0);
        __builtin_amdgcn_global_load_lds((const as1_u32*)(W0 + k0), (as3_u32*)(Bs + ldsb), 16, 0, 0);
        __builtin_amdgcn_global_load_lds((const as1_u32*)(W1 + k0), (as3_u32*)(Bs + 2048 + ldsb), 16, 0, 0);
        __syncthreads();  // barrier drain (vmcnt 0) makes LDS visible

        bf16x8 a[4], b[4];
#pragma unroll
        for (int i = 0; i < 4; ++i) a[i] = ld_bf16x8(As + (wr + i * 16 + lr) * 32 + g * 8);
#pragma unroll
        for (int j = 0; j < 4; ++j) b[j] = ld_bf16x8(Bs + (wc + j * 16 + lr) * 32 + g * 8);
#pragma unroll
        for (int i = 0; i < 4; ++i)
#pragma unroll
            for (int j = 0; j < 4; ++j) acc[i][j] = MFMA16(a[i], b[j], acc[i][j]);
    }

    // C/D layout: col = lane&15, row = (lane>>4)*4 + reg
    int g4 = g * 4;
#pragma unroll
    for (int j = 0; j < 4; ++j) {
        int col = n0 + wc + j * 16 + lr;
        float bv = bias[col];
#pragma unroll
        for (int i = 0; i < 4; ++i) {
#pragma unroll
            for (int r = 0; r < 4; ++r) {
                int row = m0 + wr + i * 16 + g4 + r;
                float v = acc[i][j][r] + bv;
                if (OUT_BF16)
                    ((unsigned short*)Cout)[(size_t)row * NC + col] = f2bf(v);
                else
                    ((float*)Cout)[(size_t)row * NC + col] = v;
            }
        }
    }
}

// ---------------- RoPE + reshape to [B,H,T,64]; Q scaled by 0.125 ----------
__global__ void rope_reshape(const unsigned short* __restrict__ qkv,
                             const float* __restrict__ ct, const float* __restrict__ st,
                             unsigned short* __restrict__ Qh,
                             unsigned short* __restrict__ Kh,
                             unsigned short* __restrict__ Vh) {
    int idx = blockIdx.x * blockDim.x + threadIdx.x;
    if (idx >= 8192 * 384) return;
    int row = idx / 384;
    int c8 = idx - row * 384;
    int col = c8 * 8;
    int sec = col >> 10;  // 0=q 1=k 2=v
    int wi = col & 1023;
    int h = wi >> 6, d = wi & 63;
    int t = row & 1023;

    uint4 raw = *(const uint4*)(qkv + (size_t)row * 3072 + col);
    size_t obase = ((size_t)((row >> 10) * 16 + h) * 1024 + t) * 64 + d;

    if (sec == 2) {
        *(uint4*)(Vh + obase) = raw;
        return;
    }
    union { uint4 v; unsigned short us[8]; } u; u.v = raw;
    float x[8];
#pragma unroll
    for (int i = 0; i < 8; ++i) x[i] = bf2f(u.us[i]);
    float scale = (sec == 0) ? 0.125f : 1.0f;  // fold 1/sqrt(hd) into Q
    union { uint4 v; unsigned short us[8]; } o;
#pragma unroll
    for (int p = 0; p < 4; ++p) {
        int fi = t * 32 + (d >> 1) + p;
        float c = ct[fi], s = st[fi];
        float e0 = (x[2 * p] * c - x[2 * p + 1] * s) * scale;
        float e1 = (x[2 * p + 1] * c + x[2 * p] * s) * scale;
        o.us[2 * p] = f2bf(e0);
        o.us[2 * p + 1] = f2bf(e1);
    }
    unsigned short* dst = (sec == 0) ? Qh : Kh;
    *(uint4*)(dst + obase) = o.v;
}

// ---------------- causal flash attention ----------------
// block = 256 thr (4 waves); wave w owns q rows [q0+16w, q0+16w+16); KV tile = 64.
// K staged via global_load_lds with pre-swizzled SOURCE + swizzled reads (rule 21);
// V transposed into LDS (reg-staged, swizzled); P transposed via per-wave LDS.
__global__ __launch_bounds__(256) void attn_fwd(const unsigned short* __restrict__ Qh,
                                                const unsigned short* __restrict__ Kh,
                                                const unsigned short* __restrict__ Vh,
                                                unsigned short* __restrict__ Yb) {
    __shared__ __attribute__((aligned(16))) unsigned short Ks[64 * 64];   // [kv][d], swizzled
    __shared__ __attribute__((aligned(16))) unsigned short Vts[64 * 64];  // [d][kv], swizzled
    __shared__ __attribute__((aligned(16))) unsigned short Ps[4 * 16 * 64];  // per-wave [16][64]

    int bid = blockIdx.x;
    int lg = (bid & 7) * 256 + (bid >> 3);  // XCD swizzle: keep a head's q-blocks on one XCD
    int bh = lg >> 4;
    int qi = lg & 15;
    int q0 = qi * 64;

    int tid = threadIdx.x, w = tid >> 6, l = tid & 63;
    int lr = l & 15, g = l >> 4;
    int ldsb = __builtin_amdgcn_readfirstlane(w * 512);

    const unsigned short* Kbase = Kh + (size_t)bh * 65536;
    const unsigned short* Vbase = Vh + (size_t)bh * 65536;

    // Q fragments (already scaled): A-frag lane = row l&15, k = (l>>4)*8 + j
    bf16x8 qf0, qf1;
    {
        const unsigned short* qp = Qh + (size_t)bh * 65536 + (size_t)(q0 + w * 16 + lr) * 64 + g * 8;
        qf0 = ld_bf16x8(qp);
        qf1 = ld_bf16x8(qp + 32);
    }

    f32x4 y[4] = {};
    float run_m[4], run_l[4];
#pragma unroll
    for (int r = 0; r < 4; ++r) { run_m[r] = -1e30f; run_l[r] = 0.0f; }

    // K staging: chunk c -> row c>>3, slot c&7; source slot = s ^ (row&7)
    int c0 = tid, c1 = tid + 256;
    const unsigned short* K0 = Kbase + (size_t)(c0 >> 3) * 64 + ((c0 ^ (c0 >> 3)) & 7) * 8;
    const unsigned short* K1 = Kbase + (size_t)(c1 >> 3) * 64 + ((c1 ^ (c1 >> 3)) & 7) * 8;
    // V reg staging: thread -> V row tid>>2, d = (tid&3)*16 .. +15
    int vr = tid >> 2, vd0 = (tid & 3) * 16;
    const unsigned short* V0 = Vbase + (size_t)vr * 64 + vd0;
    unsigned short* Pw = Ps + w * 1024;

    for (int j = 0; j <= qi; ++j) {
        int kvoff = j * 4096;  // 64 rows * 64 elems
        __syncthreads();       // previous tile fully consumed
        __builtin_amdgcn_global_load_lds((const as1_u32*)(K0 + kvoff), (as3_u32*)(Ks + ldsb), 16, 0, 0);
        __builtin_amdgcn_global_load_lds((const as1_u32*)(K1 + kvoff), (as3_u32*)(Ks + 2048 + ldsb), 16, 0, 0);
        uint4 v0 = *(const uint4*)(V0 + kvoff);
        uint4 v1 = *(const uint4*)(V0 + kvoff + 8);
        {
            union { uint4 v[2]; unsigned short us[16]; } u; u.v[0] = v0; u.v[1] = v1;
#pragma unroll
            for (int i = 0; i < 16; ++i) {
                int d = vd0 + i;
                int off = d * 128 + ((((vr >> 3) ^ d) & 7) << 4) + ((vr & 7) << 1);
                *(unsigned short*)((char*)Vts + off) = u.us[i];
            }
        }
        __syncthreads();

        // S = Q K^T : B-frag = K row (nt*16+lr), k-slot g (+4 per 32-k step)
        f32x4 s[4];
#pragma unroll
        for (int nt = 0; nt < 4; ++nt) {
            int row = nt * 16 + lr;
            bf16x8 kf0 = ld_bf16x8((const char*)Ks + row * 128 + (((g + 0) ^ (row & 7)) << 4));
            bf16x8 kf1 = ld_bf16x8((const char*)Ks + row * 128 + (((g + 4) ^ (row & 7)) << 4));
            f32x4 z = {};
            z = MFMA16(qf0, kf0, z);
            z = MFMA16(qf1, kf1, z);
            s[nt] = z;
        }

        if (j == qi) {  // diagonal tile: mask kv > q
#pragma unroll
            for (int nt = 0; nt < 4; ++nt) {
                int kv = nt * 16 + lr;
#pragma unroll
                for (int r = 0; r < 4; ++r) {
                    int qrow = w * 16 + g * 4 + r;
                    s[nt][r] = (kv > qrow) ? -1e30f : s[nt][r];
                }
            }
        }

        // online softmax over the 16-lane groups (cols of this tile)
#pragma unroll
        for (int r = 0; r < 4; ++r) {
            float tm_ = fmaxf(fmaxf(s[0][r], s[1][r]), fmaxf(s[2][r], s[3][r]));
            tm_ = fmaxf(tm_, __shfl_xor(tm_, 1));
            tm_ = fmaxf(tm_, __shfl_xor(tm_, 2));
            tm_ = fmaxf(tm_, __shfl_xor(tm_, 4));
            tm_ = fmaxf(tm_, __shfl_xor(tm_, 8));
            float nm = fmaxf(run_m[r], tm_);
            float alpha = __expf(run_m[r] - nm);
            run_m[r] = nm;
            float ts = 0.0f;
#pragma unroll
            for (int nt = 0; nt < 4; ++nt) {
                float pv = __expf(s[nt][r] - nm);
                s[nt][r] = pv;
                ts += pv;
            }
            ts += __shfl_xor(ts, 1);
            ts += __shfl_xor(ts, 2);
            ts += __shfl_xor(ts, 4);
            ts += __shfl_xor(ts, 8);
            run_l[r] = run_l[r] * alpha + ts;
#pragma unroll
            for (int nt = 0; nt < 4; ++nt) y[nt][r] *= alpha;
        }

        // P -> per-wave LDS (swizzled), then read back as A-fragments
#pragma unroll
        for (int nt = 0; nt < 4; ++nt)
#pragma unroll
            for (int r = 0; r < 4; ++r) {
                int m = g * 4 + r;
                int col = nt * 16 + lr;
                int off = m * 128 + ((((col >> 3) ^ m) & 7) << 4) + ((col & 7) << 1);
                *(unsigned short*)((char*)Pw + off) = f2bf(s[nt][r]);
            }

#pragma unroll
        for (int ks = 0; ks < 2; ++ks) {
            int slot = (g + ks * 4) ^ (lr & 7);
            bf16x8 pa = ld_bf16x8((const char*)Pw + lr * 128 + slot * 16);
#pragma unroll
            for (int nt = 0; nt < 4; ++nt) {
                int d = nt * 16 + lr;
                int vs = ((g + ks * 4) ^ d) & 7;
                bf16x8 vb = ld_bf16x8((const char*)Vts + d * 128 + (vs << 4));
                y[nt] = MFMA16(pa, vb, y[nt]);
            }
        }
    }

    // epilogue: y/l -> Yb[b*T+t][h*64+d]
    int b = bh >> 4, h = bh & 15;
#pragma unroll
    for (int r = 0; r < 4; ++r) {
        float inv = 1.0f / run_l[r];
        int row = q0 + w * 16 + g * 4 + r;
        size_t obase = ((size_t)(b * 1024 + row)) * 1024 + h * 64;
#pragma unroll
        for (int nt = 0; nt < 4; ++nt) Yb[obase + nt * 16 + lr] = f2bf(y[nt][r] * inv);
    }
}

// ---------------------------------------------------------------------------
extern "C" void kernel_launch(void* const* d_in, const int* in_sizes, int n_in,
                              void* d_out, int out_size, void* d_ws, size_t ws_size,
                              hipStream_t stream) {
    const float* x = (const float*)d_in[0];
    const float* ipw = (const float*)d_in[1];
    const float* ipb = (const float*)d_in[2];
    const float* opw = (const float*)d_in[3];
    const float* opb = (const float*)d_in[4];
    // d_in[5] = attn_mask: exactly causal, recomputed in-kernel.

    char* ws = (char*)d_ws;
    unsigned short* xb   = (unsigned short*)(ws);               // 16 MB  [8192,1024] bf16
    unsigned short* wqkv = (unsigned short*)(ws + 16777216);    // 6 MB   [3072,1024] bf16
    unsigned short* wo   = (unsigned short*)(ws + 23068672);    // 2 MB   [1024,1024] bf16
    float* ct            = (float*)(ws + 25165824);             // 128 KB [1024,32]
    float* st            = (float*)(ws + 25296896);             // 128 KB
    unsigned short* qkvb = (unsigned short*)(ws + 25427968);    // 48 MB  [8192,3072] bf16
    unsigned short* Qh   = (unsigned short*)(ws + 75759616);    // 16 MB  [B,H,T,64]
    unsigned short* Kh   = (unsigned short*)(ws + 92536832);    // 16 MB
    unsigned short* Vh   = (unsigned short*)(ws + 109314048);   // 16 MB
    unsigned short* yb   = (unsigned short*)(ws + 126091264);   // 16 MB  [8192,1024] bf16

    cast_f32_bf16<<<4096, 256, 0, stream>>>(x, xb, 1048576);
    cast_f32_bf16<<<1536, 256, 0, stream>>>(ipw, wqkv, 393216);
    cast_f32_bf16<<<512, 256, 0, stream>>>(opw, wo, 131072);
    rope_table<<<128, 256, 0, stream>>>(ct, st);

    gemm_bt<3072, true><<<1536, 256, 0, stream>>>(xb, wqkv, ipb, qkvb, 1024);
    rope_reshape<<<12288, 256, 0, stream>>>(qkvb, ct, st, Qh, Kh, Vh);
    attn_fwd<<<2048, 256, 0, stream>>>(Qh, Kh, Vh, yb);
    gemm_bt<1024, false><<<512, 256, 0, stream>>>(yb, wo, opb, d_out, 1024);
}

// Round 2
// 285.773 us; speedup vs baseline: 1.1339x; 1.1339x over previous
//
#include <hip/hip_runtime.h>
#include <stdint.h>

// ---------------------------------------------------------------------------
// MultiheadAttention fused pipeline, bf16 MFMA compute:
//   cast(x,ipw,opw) -> bf16 ; rope tables
//   gemm1: qkv = x @ ipw^T + ipb                  (bf16 out, [8192,3072])
//   rope_reshape: Q*0.125,K roped -> [B,H,T,64]   (V skipped)
//   transpose_v: qkv V-section -> Vt [B,H,64,T]
//   attn: causal flash attention, swapped-QK^T, paired q-tiles
//   gemm2: out = y @ opw^T + opb                  (fp32 out)
// B=8 T=1024 C=1024 H=16 hd=64
// ---------------------------------------------------------------------------

typedef __bf16 bf16x8 __attribute__((ext_vector_type(8)));
typedef float f32x4 __attribute__((ext_vector_type(4)));
typedef __attribute__((address_space(1))) unsigned int as1_u32;
typedef __attribute__((address_space(3))) unsigned int as3_u32;

#define MFMA16(a, b, c) __builtin_amdgcn_mfma_f32_16x16x32_bf16((a), (b), (c), 0, 0, 0)

static __device__ __forceinline__ unsigned short f2bf(float f) {
    union { float f; unsigned u; } x; x.f = f;
    return (unsigned short)((x.u + 0x7fffu + ((x.u >> 16) & 1u)) >> 16);
}
static __device__ __forceinline__ float bf2f(unsigned short u) {
    union { unsigned u; float f; } x; x.u = ((unsigned)u) << 16;
    return x.f;
}
static __device__ __forceinline__ bf16x8 ld_bf16x8(const void* p) {
    return *(const bf16x8*)p;
}
static __device__ __forceinline__ unsigned cvtpk(float lo, float hi) {
    unsigned r;
    asm("v_cvt_pk_bf16_f32 %0, %1, %2" : "=v"(r) : "v"(lo), "v"(hi));
    return r;
}

// ---------------- fp32 -> bf16 cast, 8 elems/thread ----------------
__global__ void cast_f32_bf16(const float* __restrict__ in,
                              unsigned short* __restrict__ out, int n8) {
    int i = blockIdx.x * blockDim.x + threadIdx.x;
    if (i >= n8) return;
    float4 a = ((const float4*)in)[2 * i];
    float4 b = ((const float4*)in)[2 * i + 1];
    union { unsigned short us[8]; uint4 v; } o;
    o.us[0] = f2bf(a.x); o.us[1] = f2bf(a.y); o.us[2] = f2bf(a.z); o.us[3] = f2bf(a.w);
    o.us[4] = f2bf(b.x); o.us[5] = f2bf(b.y); o.us[6] = f2bf(b.z); o.us[7] = f2bf(b.w);
    ((uint4*)out)[i] = o.v;
}

// ---------------- RoPE cos/sin tables [1024][32] fp32 ----------------
__global__ void rope_table(float* __restrict__ ct, float* __restrict__ st) {
    int idx = blockIdx.x * blockDim.x + threadIdx.x;
    if (idx >= 1024 * 32) return;
    int t = idx >> 5, i = idx & 31;
    float inv = powf(10000.0f, -(float)(2 * i) * (1.0f / 64.0f));
    float f = (float)t * inv;
    ct[idx] = cosf(f);
    st[idx] = sinf(f);
}

// ---------------- bf16 GEMM: C[m,n] = sum_k A[m,k]*W[n,k] + bias[n] --------
template <int NC, bool OUT_BF16>
__global__ __launch_bounds__(256) void gemm_bt(const unsigned short* __restrict__ A,
                                               const unsigned short* __restrict__ W,
                                               const float* __restrict__ bias,
                                               void* __restrict__ Cout, int K) {
    __shared__ __attribute__((aligned(16))) unsigned short As[128 * 32];
    __shared__ __attribute__((aligned(16))) unsigned short Bs[128 * 32];

    constexpr int NT = NC / 128;
    int nwg = gridDim.x;
    int bid = blockIdx.x;
    int lg = (bid & 7) * (nwg >> 3) + (bid >> 3);  // XCD swizzle (nwg % 8 == 0)
    int tm = lg / NT, tn = lg % NT;
    int m0 = tm * 128, n0 = tn * 128;

    int tid = threadIdx.x;
    int w = tid >> 6, l = tid & 63;
    int lr = l & 15, g = l >> 4;
    int ldsb = __builtin_amdgcn_readfirstlane(w * 512);

    int c0 = tid, c1 = tid + 256;
    const unsigned short* A0 = A + (size_t)(m0 + (c0 >> 2)) * K + (c0 & 3) * 8;
    const unsigned short* A1 = A + (size_t)(m0 + (c1 >> 2)) * K + (c1 & 3) * 8;
    const unsigned short* W0 = W + (size_t)(n0 + (c0 >> 2)) * K + (c0 & 3) * 8;
    const unsigned short* W1 = W + (size_t)(n0 + (c1 >> 2)) * K + (c1 & 3) * 8;

    f32x4 acc[4][4] = {};
    int wr = (w >> 1) * 64, wc = (w & 1) * 64;

    for (int k0 = 0; k0 < K; k0 += 32) {
        __syncthreads();
        __builtin_amdgcn_global_load_lds((const as1_u32*)(A0 + k0), (as3_u32*)(As + ldsb), 16, 0, 0);
        __builtin_amdgcn_global_load_lds((const as1_u32*)(A1 + k0), (as3_u32*)(As + 2048 + ldsb), 16, 0, 0);
        __builtin_amdgcn_global_load_lds((const as1_u32*)(W0 + k0), (as3_u32*)(Bs + ldsb), 16, 0, 0);
        __builtin_amdgcn_global_load_lds((const as1_u32*)(W1 + k0), (as3_u32*)(Bs + 2048 + ldsb), 16, 0, 0);
        __syncthreads();

        bf16x8 a[4], b[4];
#pragma unroll
        for (int i = 0; i < 4; ++i) a[i] = ld_bf16x8(As + (wr + i * 16 + lr) * 32 + g * 8);
#pragma unroll
        for (int j = 0; j < 4; ++j) b[j] = ld_bf16x8(Bs + (wc + j * 16 + lr) * 32 + g * 8);
#pragma unroll
        for (int i = 0; i < 4; ++i)
#pragma unroll
            for (int j = 0; j < 4; ++j) acc[i][j] = MFMA16(a[i], b[j], acc[i][j]);
    }

    int g4 = g * 4;
#pragma unroll
    for (int j = 0; j < 4; ++j) {
        int col = n0 + wc + j * 16 + lr;
        float bv = bias[col];
#pragma unroll
        for (int i = 0; i < 4; ++i) {
#pragma unroll
            for (int r = 0; r < 4; ++r) {
                int row = m0 + wr + i * 16 + g4 + r;
                float v = acc[i][j][r] + bv;
                if (OUT_BF16)
                    ((unsigned short*)Cout)[(size_t)row * NC + col] = f2bf(v);
                else
                    ((float*)Cout)[(size_t)row * NC + col] = v;
            }
        }
    }
}

// ---------------- RoPE + reshape Q,K only -> [B,H,T,64]; Q scaled 0.125 ----
__global__ void rope_reshape(const unsigned short* __restrict__ qkv,
                             const float* __restrict__ ct, const float* __restrict__ st,
                             unsigned short* __restrict__ Qh,
                             unsigned short* __restrict__ Kh) {
    int idx = blockIdx.x * blockDim.x + threadIdx.x;
    if (idx >= 8192 * 256) return;
    int row = idx >> 8;
    int col = (idx & 255) * 8;   // 0..2047: q,k sections only
    int sec = col >> 10;         // 0=q 1=k
    int wi = col & 1023;
    int h = wi >> 6, d = wi & 63;
    int t = row & 1023;

    uint4 raw = *(const uint4*)(qkv + (size_t)row * 3072 + col);
    size_t obase = ((size_t)((row >> 10) * 16 + h) * 1024 + t) * 64 + d;

    union { uint4 v; unsigned short us[8]; } u; u.v = raw;
    float x[8];
#pragma unroll
    for (int i = 0; i < 8; ++i) x[i] = bf2f(u.us[i]);
    float scale = (sec == 0) ? 0.125f : 1.0f;
    union { uint4 v; unsigned short us[8]; } o;
#pragma unroll
    for (int p = 0; p < 4; ++p) {
        int fi = t * 32 + (d >> 1) + p;
        float c = ct[fi], s = st[fi];
        float e0 = (x[2 * p] * c - x[2 * p + 1] * s) * scale;
        float e1 = (x[2 * p + 1] * c + x[2 * p] * s) * scale;
        o.us[2 * p] = f2bf(e0);
        o.us[2 * p + 1] = f2bf(e1);
    }
    unsigned short* dst = (sec == 0) ? Qh : Kh;
    *(uint4*)(dst + obase) = o.v;
}

// ---------------- V transpose: qkv[:,2048+h*64+d] -> Vt[b,h,d,t] -----------
__global__ __launch_bounds__(256) void transpose_v(const unsigned short* __restrict__ qkv,
                                                   unsigned short* __restrict__ Vt) {
    __shared__ unsigned short Ts[64 * 67];
    int bid = blockIdx.x;  // 128 bh * 16 t-tiles
    int bh = bid >> 4, tt = bid & 15;
    int b = bh >> 4, h = bh & 15;
    int t0 = tt * 64;
    int tid = threadIdx.x;
#pragma unroll
    for (int cc = 0; cc < 2; ++cc) {
        int c = tid + cc * 256;
        int trow = c >> 3, d8 = (c & 7) * 8;
        uint4 v = *(const uint4*)(qkv + (size_t)(b * 1024 + t0 + trow) * 3072 + 2048 + h * 64 + d8);
        union { uint4 v; unsigned short us[8]; } u; u.v = v;
#pragma unroll
        for (int i = 0; i < 8; ++i) Ts[trow * 67 + d8 + i] = u.us[i];
    }
    __syncthreads();
#pragma unroll
    for (int cc = 0; cc < 2; ++cc) {
        int c = tid + cc * 256;
        int drow = c >> 3, t8 = (c & 7) * 8;
        union { uint4 v; unsigned short us[8]; } u;
#pragma unroll
        for (int i = 0; i < 8; ++i) u.us[i] = Ts[(t8 + i) * 67 + drow];
        *(uint4*)(Vt + (size_t)bh * 65536 + (size_t)drow * 1024 + t0 + t8) = u.v;
    }
}

// ---------------- causal flash attention (swapped QK^T, paired q-tiles) ----
// Block = 4 waves; wave w owns q rows w*16..+16 of TWO q-tiles (qa=p, qb=15-p).
// S^T = mfma(K,Q): lane holds q=lane&15, kv = nt*16+g*4+r -> in-register softmax.
// PV: A = V^T (staged via gload_lds + XOR swizzle), B = P^T packed lane-local
// with k-slot permutation pi(g,j) = g*4+(j&3)+16*(j>>2).
__device__ __forceinline__ void attn_tile(const unsigned short* Ks, const unsigned short* Vs,
                                          bf16x8 q0f, bf16x8 q1f, f32x4 (&y)[4],
                                          float& rm, float& rl,
                                          int lr, int g, bool diag, int wq) {
    const char* kc = (const char*)Ks;
    const char* vc = (const char*)Vs;
    int l7 = lr & 7;
    int kof0 = lr * 128 + ((g ^ l7) << 4);
    int kof1 = lr * 128 + (((g + 4) ^ l7) << 4);
    f32x4 s[4];
#pragma unroll
    for (int nt = 0; nt < 4; ++nt) {
        bf16x8 kf0 = ld_bf16x8(kc + nt * 2048 + kof0);
        bf16x8 kf1 = ld_bf16x8(kc + nt * 2048 + kof1);
        f32x4 z = {};
        z = MFMA16(kf0, q0f, z);
        z = MFMA16(kf1, q1f, z);
        s[nt] = z;
    }
    if (diag) {
#pragma unroll
        for (int nt = 0; nt < 4; ++nt)
#pragma unroll
            for (int r = 0; r < 4; ++r)
                if (nt * 16 + g * 4 + r > wq + lr) s[nt][r] = -3e38f;
    }
    // online softmax: lane-local 16 values + 2 shuffles
    float tm;
    {
        f32x4 m4;
#pragma unroll
        for (int r = 0; r < 4; ++r) m4[r] = fmaxf(fmaxf(s[0][r], s[1][r]), fmaxf(s[2][r], s[3][r]));
        tm = fmaxf(fmaxf(m4[0], m4[1]), fmaxf(m4[2], m4[3]));
    }
    tm = fmaxf(tm, __shfl_xor(tm, 16));
    tm = fmaxf(tm, __shfl_xor(tm, 32));
    float nm = fmaxf(rm, tm);
    float alpha = __expf(rm - nm);
    rm = nm;
    float ts = 0.f;
#pragma unroll
    for (int nt = 0; nt < 4; ++nt)
#pragma unroll
        for (int r = 0; r < 4; ++r) { float pv = __expf(s[nt][r] - nm); s[nt][r] = pv; ts += pv; }
    ts += __shfl_xor(ts, 16);
    ts += __shfl_xor(ts, 32);
    rl = rl * alpha + ts;
#pragma unroll
    for (int nt = 0; nt < 4; ++nt) y[nt] *= alpha;
    // pack P^T lane-local (zero shuffles)
    union { unsigned u[4]; bf16x8 v; } pf0, pf1;
    pf0.u[0] = cvtpk(s[0][0], s[0][1]); pf0.u[1] = cvtpk(s[0][2], s[0][3]);
    pf0.u[2] = cvtpk(s[1][0], s[1][1]); pf0.u[3] = cvtpk(s[1][2], s[1][3]);
    pf1.u[0] = cvtpk(s[2][0], s[2][1]); pf1.u[1] = cvtpk(s[2][2], s[2][3]);
    pf1.u[2] = cvtpk(s[3][0], s[3][1]); pf1.u[3] = cvtpk(s[3][2], s[3][3]);
    // PV: vfrag slot (g,j) holds V^T[d][pi(g,j)+32ks]
    int s0 = g >> 1, h8 = (g & 1) * 8;
    int vo0 = lr * 128 + h8 + (((s0 + 0) ^ l7) << 4);
    int vo1 = lr * 128 + h8 + (((s0 + 2) ^ l7) << 4);
    int vo2 = lr * 128 + h8 + (((s0 + 4) ^ l7) << 4);
    int vo3 = lr * 128 + h8 + (((s0 + 6) ^ l7) << 4);
#pragma unroll
    for (int nt = 0; nt < 4; ++nt) {
        union { uint2 u2[2]; bf16x8 v; } vf;
        vf.u2[0] = *(const uint2*)(vc + nt * 2048 + vo0);
        vf.u2[1] = *(const uint2*)(vc + nt * 2048 + vo1);
        y[nt] = MFMA16(vf.v, pf0.v, y[nt]);
        union { uint2 u2[2]; bf16x8 v; } vg;
        vg.u2[0] = *(const uint2*)(vc + nt * 2048 + vo2);
        vg.u2[1] = *(const uint2*)(vc + nt * 2048 + vo3);
        y[nt] = MFMA16(vg.v, pf1.v, y[nt]);
    }
}

__device__ __forceinline__ void attn_epilogue(unsigned short* smem, unsigned short* __restrict__ Yb,
                                              f32x4 (&y)[4], float rl, int qtile,
                                              int b, int hh, int w, int lr, int g, int tid) {
    __syncthreads();
    float inv = 1.0f / rl;
    char* ep = (char*)smem;
#pragma unroll
    for (int nt = 0; nt < 4; ++nt) {
        uint2 pr;
        pr.x = cvtpk(y[nt][0] * inv, y[nt][1] * inv);
        pr.y = cvtpk(y[nt][2] * inv, y[nt][3] * inv);
        *(uint2*)(ep + (w * 16 + lr) * 144 + (nt * 16 + g * 4) * 2) = pr;  // [64 q][72 d]
    }
    __syncthreads();
    int q = tid >> 2, dc = (tid & 3) * 16;
    uint4 u0 = *(const uint4*)(ep + q * 144 + dc * 2);
    uint4 u1 = *(const uint4*)(ep + q * 144 + dc * 2 + 16);
    size_t orow = ((size_t)(b * 1024 + qtile * 64 + q)) * 1024 + hh * 64 + dc;
    *(uint4*)(Yb + orow) = u0;
    *(uint4*)(Yb + orow + 8) = u1;
}

__global__ __launch_bounds__(256) void attn_fwd(const unsigned short* __restrict__ Qh,
                                                const unsigned short* __restrict__ Kh,
                                                const unsigned short* __restrict__ Vt,
                                                unsigned short* __restrict__ Yb) {
    __shared__ __attribute__((aligned(16))) unsigned short smem[8192];  // Ks|Vs (16KB), reused by epilogue
    unsigned short* Ks = smem;
    unsigned short* Vs = smem + 4096;

    int bid = blockIdx.x;
    int lg = (bid & 7) * 128 + (bid >> 3);  // 1024 blocks, XCD swizzle
    int bh = lg >> 3, p = lg & 7;
    int qa = p, qb = 15 - p;

    int tid = threadIdx.x, w = tid >> 6, l = tid & 63;
    int lr = l & 15, g = l >> 4;
    int ldsb = __builtin_amdgcn_readfirstlane(w * 512);

    size_t bh64 = (size_t)bh * 65536;
    const unsigned short* qbase = Qh + bh64 + (size_t)(w * 16 + lr) * 64 + g * 8;
    bf16x8 qA0 = ld_bf16x8(qbase + qa * 4096);
    bf16x8 qA1 = ld_bf16x8(qbase + qa * 4096 + 32);
    bf16x8 qB0 = ld_bf16x8(qbase + qb * 4096);
    bf16x8 qB1 = ld_bf16x8(qbase + qb * 4096 + 32);

    f32x4 yA[4] = {}, yB[4] = {};
    float mA = -3e38f, lA = 0.f, mB = -3e38f, lB = 0.f;

    int c0 = tid, c1 = tid + 256;
    const unsigned short* K0 = Kh + bh64 + (c0 >> 3) * 64 + ((c0 ^ (c0 >> 3)) & 7) * 8;
    const unsigned short* K1 = Kh + bh64 + (c1 >> 3) * 64 + ((c1 ^ (c1 >> 3)) & 7) * 8;
    const unsigned short* V0 = Vt + bh64 + (c0 >> 3) * 1024 + ((c0 ^ (c0 >> 3)) & 7) * 8;
    const unsigned short* V1 = Vt + bh64 + (c1 >> 3) * 1024 + ((c1 ^ (c1 >> 3)) & 7) * 8;

    for (int t = 0; t <= qb; ++t) {
        __syncthreads();
        __builtin_amdgcn_global_load_lds((const as1_u32*)(K0 + t * 4096), (as3_u32*)(Ks + ldsb), 16, 0, 0);
        __builtin_amdgcn_global_load_lds((const as1_u32*)(K1 + t * 4096), (as3_u32*)(Ks + 2048 + ldsb), 16, 0, 0);
        __builtin_amdgcn_global_load_lds((const as1_u32*)(V0 + t * 64), (as3_u32*)(Vs + ldsb), 16, 0, 0);
        __builtin_amdgcn_global_load_lds((const as1_u32*)(V1 + t * 64), (as3_u32*)(Vs + 2048 + ldsb), 16, 0, 0);
        __syncthreads();

        if (t <= qa)
            attn_tile(Ks, Vs, qA0, qA1, yA, mA, lA, lr, g, t == qa, w * 16);
        attn_tile(Ks, Vs, qB0, qB1, yB, mB, lB, lr, g, t == qb, w * 16);
    }

    int b = bh >> 4, hh = bh & 15;
    attn_epilogue(smem, Yb, yA, lA, qa, b, hh, w, lr, g, tid);
    attn_epilogue(smem, Yb, yB, lB, qb, b, hh, w, lr, g, tid);
}

// ---------------------------------------------------------------------------
extern "C" void kernel_launch(void* const* d_in, const int* in_sizes, int n_in,
                              void* d_out, int out_size, void* d_ws, size_t ws_size,
                              hipStream_t stream) {
    const float* x = (const float*)d_in[0];
    const float* ipw = (const float*)d_in[1];
    const float* ipb = (const float*)d_in[2];
    const float* opw = (const float*)d_in[3];
    const float* opb = (const float*)d_in[4];

    char* ws = (char*)d_ws;
    unsigned short* xb   = (unsigned short*)(ws);               // 16 MB  [8192,1024] bf16
    unsigned short* wqkv = (unsigned short*)(ws + 16777216);    // 6 MB   [3072,1024]
    unsigned short* wo   = (unsigned short*)(ws + 23068672);    // 2 MB   [1024,1024]
    float* ct            = (float*)(ws + 25165824);             // 128 KB
    float* st            = (float*)(ws + 25296896);             // 128 KB
    unsigned short* qkvb = (unsigned short*)(ws + 25427968);    // 48 MB  [8192,3072]
    unsigned short* Qh   = (unsigned short*)(ws + 75759616);    // 16 MB  [B,H,T,64]
    unsigned short* Kh   = (unsigned short*)(ws + 92536832);    // 16 MB  [B,H,T,64]
    unsigned short* Vt   = (unsigned short*)(ws + 109314048);   // 16 MB  [B,H,64,T]
    unsigned short* yb   = (unsigned short*)(ws + 126091264);   // 16 MB  [8192,1024]

    cast_f32_bf16<<<4096, 256, 0, stream>>>(x, xb, 1048576);
    cast_f32_bf16<<<1536, 256, 0, stream>>>(ipw, wqkv, 393216);
    cast_f32_bf16<<<512, 256, 0, stream>>>(opw, wo, 131072);
    rope_table<<<128, 256, 0, stream>>>(ct, st);

    gemm_bt<3072, true><<<1536, 256, 0, stream>>>(xb, wqkv, ipb, qkvb, 1024);
    rope_reshape<<<8192, 256, 0, stream>>>(qkvb, ct, st, Qh, Kh);
    transpose_v<<<2048, 256, 0, stream>>>(qkvb, Vt);
    attn_fwd<<<1024, 256, 0, stream>>>(Qh, Kh, Vt, yb);
    gemm_bt<1024, false><<<512, 256, 0, stream>>>(yb, wo, opb, d_out, 1024);
}

// Round 4
// 277.257 us; speedup vs baseline: 1.1687x; 1.0307x over previous
//
#include <hip/hip_runtime.h>
#include <stdint.h>

// ---------------------------------------------------------------------------
// MultiheadAttention fused pipeline, bf16 MFMA compute:
//   cast(x,ipw,opw) -> bf16 ; rope tables
//   gemm1_8ph: qkv = x @ ipw^T + ipb   (256^2 8-phase counted-vmcnt template)
//   rope_reshape: Q*0.125,K roped -> [B,H,T,64]   (V skipped)
//   transpose_v: qkv V-section -> Vt [B,H,64,T]
//   attn: causal flash attention, swapped-QK^T, paired q-tiles
//   gemm2: out = y @ opw^T + opb                  (fp32 out, m97 structure)
// B=8 T=1024 C=1024 H=16 hd=64
// ---------------------------------------------------------------------------

typedef __bf16 bf16x8 __attribute__((ext_vector_type(8)));
typedef float f32x4 __attribute__((ext_vector_type(4)));
typedef __attribute__((address_space(1))) unsigned int as1_u32;
typedef __attribute__((address_space(3))) unsigned int as3_u32;

#define MFMA16(a, b, c) __builtin_amdgcn_mfma_f32_16x16x32_bf16((a), (b), (c), 0, 0, 0)

static __device__ __forceinline__ unsigned short f2bf(float f) {
    union { float f; unsigned u; } x; x.f = f;
    return (unsigned short)((x.u + 0x7fffu + ((x.u >> 16) & 1u)) >> 16);
}
static __device__ __forceinline__ float bf2f(unsigned short u) {
    union { unsigned u; float f; } x; x.u = ((unsigned)u) << 16;
    return x.f;
}
static __device__ __forceinline__ bf16x8 ld_bf16x8(const void* p) {
    return *(const bf16x8*)p;
}
static __device__ __forceinline__ unsigned cvtpk(float lo, float hi) {
    unsigned r;
    asm("v_cvt_pk_bf16_f32 %0, %1, %2" : "=v"(r) : "v"(lo), "v"(hi));
    return r;
}

// ---------------- fp32 -> bf16 cast, 8 elems/thread ----------------
__global__ void cast_f32_bf16(const float* __restrict__ in,
                              unsigned short* __restrict__ out, int n8) {
    int i = blockIdx.x * blockDim.x + threadIdx.x;
    if (i >= n8) return;
    float4 a = ((const float4*)in)[2 * i];
    float4 b = ((const float4*)in)[2 * i + 1];
    union { unsigned short us[8]; uint4 v; } o;
    o.us[0] = f2bf(a.x); o.us[1] = f2bf(a.y); o.us[2] = f2bf(a.z); o.us[3] = f2bf(a.w);
    o.us[4] = f2bf(b.x); o.us[5] = f2bf(b.y); o.us[6] = f2bf(b.z); o.us[7] = f2bf(b.w);
    ((uint4*)out)[i] = o.v;
}

// ---------------- RoPE cos/sin tables [1024][32] fp32 ----------------
__global__ void rope_table(float* __restrict__ ct, float* __restrict__ st) {
    int idx = blockIdx.x * blockDim.x + threadIdx.x;
    if (idx >= 1024 * 32) return;
    int t = idx >> 5, i = idx & 31;
    float inv = powf(10000.0f, -(float)(2 * i) * (1.0f / 64.0f));
    float f = (float)t * inv;
    ct[idx] = cosf(f);
    st[idx] = sinf(f);
}

// ---------------- gemm1: 256x256 8-phase template, K=1024, N=3072 ----------
// K-split: k-half = 32 cols; LDS ring of 4 slots per matrix, slot = [256][32]
// bf16 stored as [128 lds_rows][64 cols] (row-pair interleave), slot-XOR
// swizzle s_st = s_log ^ (lds_row&7) on BOTH write-source and read (rule 21).
// 8 waves = 2M x 4N, per-wave 128x64 out. Per phase: ds_read subtile +
// 2 global_load_lds + barrier + setprio{16 MFMA} + barrier. vmcnt(8) once
// per k-half (3 halves in flight), never 0 until tail.
__global__ __launch_bounds__(512, 2) void gemm1_8ph(const unsigned short* __restrict__ A,
                                                    const unsigned short* __restrict__ W,
                                                    const float* __restrict__ bias,
                                                    unsigned short* __restrict__ Cout) {
    __shared__ __attribute__((aligned(16))) char lds[131072];  // A ring 64KB | B ring 64KB
    constexpr int NH = 32;   // K / 32
    constexpr int NTN = 12;  // N / 256

    int nwg = gridDim.x;  // 384
    int bid = blockIdx.x;
    int lg = (bid & 7) * (nwg >> 3) + (bid >> 3);  // XCD swizzle (384 % 8 == 0)
    int tm = lg / NTN, tn = lg % NTN;
    int m0 = tm * 256, n0 = tn * 256;

    int tid = threadIdx.x;
    int w = tid >> 6, l = tid & 63;
    int lr = l & 15, g = l >> 4;
    int wm = w >> 2, wn = w & 3;
    int ldsb = __builtin_amdgcn_readfirstlane(w * 1024);  // byte, wave-uniform

    // staging: chunk c -> lds_row c>>3, stored slot c&7; source is inverse-swizzled
    auto srcoff = [](int c) {
        int row = c >> 3;
        int sl = (c & 7) ^ (row & 7);          // logical slot
        int rg = (row << 1) | (sl >> 2);       // global row within tile
        int cg = (sl & 3) * 8;                 // col within k-half
        return rg * 1024 + cg;                 // elements (row stride K=1024)
    };
    int c0 = tid, c1 = tid + 512;
    const unsigned short* pA0 = A + (size_t)m0 * 1024 + srcoff(c0);
    const unsigned short* pA1 = A + (size_t)m0 * 1024 + srcoff(c1);
    const unsigned short* pB0 = W + (size_t)n0 * 1024 + srcoff(c0);
    const unsigned short* pB1 = W + (size_t)n0 * 1024 + srcoff(c1);

    // read bases: lane holds row (base+lr), k-chunk g*8 of the 32-wide k-half
    int lr2 = lr >> 1;
    int sst16 = ((((lr & 1) << 2) + g) ^ lr2) << 4;
    int aBase = (wm * 64 + lr2) * 128 + sst16;  // byte within A slot (+fm*1024)
    int bBase = (wn * 32 + lr2) * 128 + sst16;  // byte within B slot (+fn*1024)

    f32x4 acc[8][4] = {};

    // prologue: stage k-halves 0..2 (slots 0..2), wait for half 0
    for (int js = 0; js < 3; ++js) {
        char* Ad = lds + js * 16384;
        char* Bd = lds + 65536 + js * 16384;
        __builtin_amdgcn_global_load_lds((const as1_u32*)(pA0 + js * 32), (as3_u32*)(Ad + ldsb), 16, 0, 0);
        __builtin_amdgcn_global_load_lds((const as1_u32*)(pA1 + js * 32), (as3_u32*)(Ad + 8192 + ldsb), 16, 0, 0);
        __builtin_amdgcn_global_load_lds((const as1_u32*)(pB0 + js * 32), (as3_u32*)(Bd + ldsb), 16, 0, 0);
        __builtin_amdgcn_global_load_lds((const as1_u32*)(pB1 + js * 32), (as3_u32*)(Bd + 8192 + ldsb), 16, 0, 0);
    }
    asm volatile("s_waitcnt vmcnt(8)" ::: "memory");
    __builtin_amdgcn_s_barrier();

#pragma unroll 4
    for (int j = 0; j < NH; ++j) {
        const char* Asl = lds + (j & 3) * 16384;
        const char* Bsl = lds + 65536 + (j & 3) * 16384;
        int js = j + 3;                       // stage target k-half
        char* Ad = lds + (js & 3) * 16384;    // == slot j-1: dead since last iter
        char* Bd = lds + 65536 + (js & 3) * 16384;
        bf16x8 aa[4], bb[4];

        // ---- phase 0: B frags + A lower-half frags; stage A(j+3) ----
#pragma unroll
        for (int fn = 0; fn < 4; ++fn) bb[fn] = ld_bf16x8(Bsl + bBase + fn * 1024);
#pragma unroll
        for (int fm = 0; fm < 4; ++fm) aa[fm] = ld_bf16x8(Asl + aBase + fm * 1024);
        if (js < NH) {
            __builtin_amdgcn_global_load_lds((const as1_u32*)(pA0 + js * 32), (as3_u32*)(Ad + ldsb), 16, 0, 0);
            __builtin_amdgcn_global_load_lds((const as1_u32*)(pA1 + js * 32), (as3_u32*)(Ad + 8192 + ldsb), 16, 0, 0);
        }
        __builtin_amdgcn_s_barrier();
        __builtin_amdgcn_s_setprio(1);
#pragma unroll
        for (int fm = 0; fm < 4; ++fm)
#pragma unroll
            for (int fn = 0; fn < 4; ++fn) acc[fm][fn] = MFMA16(aa[fm], bb[fn], acc[fm][fn]);
        __builtin_amdgcn_s_setprio(0);
        __builtin_amdgcn_s_barrier();

        // ---- phase 1: A upper-half frags (reuse bb); stage B(j+3) ----
#pragma unroll
        for (int fm = 0; fm < 4; ++fm) aa[fm] = ld_bf16x8(Asl + aBase + (fm + 4) * 1024);
        if (js < NH) {
            __builtin_amdgcn_global_load_lds((const as1_u32*)(pB0 + js * 32), (as3_u32*)(Bd + ldsb), 16, 0, 0);
            __builtin_amdgcn_global_load_lds((const as1_u32*)(pB1 + js * 32), (as3_u32*)(Bd + 8192 + ldsb), 16, 0, 0);
        }
        __builtin_amdgcn_s_barrier();
        __builtin_amdgcn_s_setprio(1);
#pragma unroll
        for (int fm = 0; fm < 4; ++fm)
#pragma unroll
            for (int fn = 0; fn < 4; ++fn) acc[fm + 4][fn] = MFMA16(aa[fm], bb[fn], acc[fm + 4][fn]);
        __builtin_amdgcn_s_setprio(0);
        // counted wait: need k-half j+1 landed; keep 2 halves (8 loads) in flight
        if (j + 3 < NH)      asm volatile("s_waitcnt vmcnt(8)" ::: "memory");
        else if (j + 2 < NH) asm volatile("s_waitcnt vmcnt(4)" ::: "memory");
        else if (j + 1 < NH) asm volatile("s_waitcnt vmcnt(0)" ::: "memory");
        __builtin_amdgcn_s_barrier();
    }

    // epilogue: C/D layout col=lane&15, row=(lane>>4)*4+reg
#pragma unroll
    for (int fn = 0; fn < 4; ++fn) {
        int col = n0 + wn * 64 + fn * 16 + lr;
        float bv = bias[col];
#pragma unroll
        for (int fm = 0; fm < 8; ++fm) {
            int row = m0 + wm * 128 + fm * 16 + g * 4;
#pragma unroll
            for (int r = 0; r < 4; ++r)
                Cout[(size_t)(row + r) * 3072 + col] = f2bf(acc[fm][fn][r] + bv);
        }
    }
}

// ---------------- bf16 GEMM (m97 128^2): C = A @ W^T + bias ----------------
template <int NC, bool OUT_BF16>
__global__ __launch_bounds__(256) void gemm_bt(const unsigned short* __restrict__ A,
                                               const unsigned short* __restrict__ W,
                                               const float* __restrict__ bias,
                                               void* __restrict__ Cout, int K) {
    __shared__ __attribute__((aligned(16))) unsigned short As[128 * 32];
    __shared__ __attribute__((aligned(16))) unsigned short Bs[128 * 32];

    constexpr int NT = NC / 128;
    int nwg = gridDim.x;
    int bid = blockIdx.x;
    int lg = (bid & 7) * (nwg >> 3) + (bid >> 3);
    int tm = lg / NT, tn = lg % NT;
    int m0 = tm * 128, n0 = tn * 128;

    int tid = threadIdx.x;
    int w = tid >> 6, l = tid & 63;
    int lr = l & 15, g = l >> 4;
    int ldsb = __builtin_amdgcn_readfirstlane(w * 512);

    int c0 = tid, c1 = tid + 256;
    const unsigned short* A0 = A + (size_t)(m0 + (c0 >> 2)) * K + (c0 & 3) * 8;
    const unsigned short* A1 = A + (size_t)(m0 + (c1 >> 2)) * K + (c1 & 3) * 8;
    const unsigned short* W0 = W + (size_t)(n0 + (c0 >> 2)) * K + (c0 & 3) * 8;
    const unsigned short* W1 = W + (size_t)(n0 + (c1 >> 2)) * K + (c1 & 3) * 8;

    f32x4 acc[4][4] = {};
    int wr = (w >> 1) * 64, wc = (w & 1) * 64;

    for (int k0 = 0; k0 < K; k0 += 32) {
        __syncthreads();
        __builtin_amdgcn_global_load_lds((const as1_u32*)(A0 + k0), (as3_u32*)(As + ldsb), 16, 0, 0);
        __builtin_amdgcn_global_load_lds((const as1_u32*)(A1 + k0), (as3_u32*)(As + 2048 + ldsb), 16, 0, 0);
        __builtin_amdgcn_global_load_lds((const as1_u32*)(W0 + k0), (as3_u32*)(Bs + ldsb), 16, 0, 0);
        __builtin_amdgcn_global_load_lds((const as1_u32*)(W1 + k0), (as3_u32*)(Bs + 2048 + ldsb), 16, 0, 0);
        __syncthreads();

        bf16x8 a[4], b[4];
#pragma unroll
        for (int i = 0; i < 4; ++i) a[i] = ld_bf16x8(As + (wr + i * 16 + lr) * 32 + g * 8);
#pragma unroll
        for (int j = 0; j < 4; ++j) b[j] = ld_bf16x8(Bs + (wc + j * 16 + lr) * 32 + g * 8);
#pragma unroll
        for (int i = 0; i < 4; ++i)
#pragma unroll
            for (int j = 0; j < 4; ++j) acc[i][j] = MFMA16(a[i], b[j], acc[i][j]);
    }

    int g4 = g * 4;
#pragma unroll
    for (int j = 0; j < 4; ++j) {
        int col = n0 + wc + j * 16 + lr;
        float bv = bias[col];
#pragma unroll
        for (int i = 0; i < 4; ++i) {
#pragma unroll
            for (int r = 0; r < 4; ++r) {
                int row = m0 + wr + i * 16 + g4 + r;
                float v = acc[i][j][r] + bv;
                if (OUT_BF16)
                    ((unsigned short*)Cout)[(size_t)row * NC + col] = f2bf(v);
                else
                    ((float*)Cout)[(size_t)row * NC + col] = v;
            }
        }
    }
}

// ---------------- RoPE + reshape Q,K only -> [B,H,T,64]; Q scaled 0.125 ----
__global__ void rope_reshape(const unsigned short* __restrict__ qkv,
                             const float* __restrict__ ct, const float* __restrict__ st,
                             unsigned short* __restrict__ Qh,
                             unsigned short* __restrict__ Kh) {
    int idx = blockIdx.x * blockDim.x + threadIdx.x;
    if (idx >= 8192 * 256) return;
    int row = idx >> 8;
    int col = (idx & 255) * 8;
    int sec = col >> 10;
    int wi = col & 1023;
    int h = wi >> 6, d = wi & 63;
    int t = row & 1023;

    uint4 raw = *(const uint4*)(qkv + (size_t)row * 3072 + col);
    size_t obase = ((size_t)((row >> 10) * 16 + h) * 1024 + t) * 64 + d;

    union { uint4 v; unsigned short us[8]; } u; u.v = raw;
    float x[8];
#pragma unroll
    for (int i = 0; i < 8; ++i) x[i] = bf2f(u.us[i]);
    float scale = (sec == 0) ? 0.125f : 1.0f;
    union { uint4 v; unsigned short us[8]; } o;
#pragma unroll
    for (int p = 0; p < 4; ++p) {
        int fi = t * 32 + (d >> 1) + p;
        float c = ct[fi], s = st[fi];
        float e0 = (x[2 * p] * c - x[2 * p + 1] * s) * scale;
        float e1 = (x[2 * p + 1] * c + x[2 * p] * s) * scale;
        o.us[2 * p] = f2bf(e0);
        o.us[2 * p + 1] = f2bf(e1);
    }
    unsigned short* dst = (sec == 0) ? Qh : Kh;
    *(uint4*)(dst + obase) = o.v;
}

// ---------------- V transpose: qkv[:,2048+h*64+d] -> Vt[b,h,d,t] -----------
__global__ __launch_bounds__(256) void transpose_v(const unsigned short* __restrict__ qkv,
                                                   unsigned short* __restrict__ Vt) {
    __shared__ unsigned short Ts[64 * 67];
    int bid = blockIdx.x;
    int bh = bid >> 4, tt = bid & 15;
    int b = bh >> 4, h = bh & 15;
    int t0 = tt * 64;
    int tid = threadIdx.x;
#pragma unroll
    for (int cc = 0; cc < 2; ++cc) {
        int c = tid + cc * 256;
        int trow = c >> 3, d8 = (c & 7) * 8;
        uint4 v = *(const uint4*)(qkv + (size_t)(b * 1024 + t0 + trow) * 3072 + 2048 + h * 64 + d8);
        union { uint4 v; unsigned short us[8]; } u; u.v = v;
#pragma unroll
        for (int i = 0; i < 8; ++i) Ts[trow * 67 + d8 + i] = u.us[i];
    }
    __syncthreads();
#pragma unroll
    for (int cc = 0; cc < 2; ++cc) {
        int c = tid + cc * 256;
        int drow = c >> 3, t8 = (c & 7) * 8;
        union { uint4 v; unsigned short us[8]; } u;
#pragma unroll
        for (int i = 0; i < 8; ++i) u.us[i] = Ts[(t8 + i) * 67 + drow];
        *(uint4*)(Vt + (size_t)bh * 65536 + (size_t)drow * 1024 + t0 + t8) = u.v;
    }
}

// ---------------- causal flash attention (swapped QK^T, paired q-tiles) ----
__device__ __forceinline__ void attn_tile(const unsigned short* Ks, const unsigned short* Vs,
                                          bf16x8 q0f, bf16x8 q1f, f32x4 (&y)[4],
                                          float& rm, float& rl,
                                          int lr, int g, bool diag, int wq) {
    const char* kc = (const char*)Ks;
    const char* vc = (const char*)Vs;
    int l7 = lr & 7;
    int kof0 = lr * 128 + ((g ^ l7) << 4);
    int kof1 = lr * 128 + (((g + 4) ^ l7) << 4);
    f32x4 s[4];
#pragma unroll
    for (int nt = 0; nt < 4; ++nt) {
        bf16x8 kf0 = ld_bf16x8(kc + nt * 2048 + kof0);
        bf16x8 kf1 = ld_bf16x8(kc + nt * 2048 + kof1);
        f32x4 z = {};
        z = MFMA16(kf0, q0f, z);
        z = MFMA16(kf1, q1f, z);
        s[nt] = z;
    }
    if (diag) {
#pragma unroll
        for (int nt = 0; nt < 4; ++nt)
#pragma unroll
            for (int r = 0; r < 4; ++r)
                if (nt * 16 + g * 4 + r > wq + lr) s[nt][r] = -3e38f;
    }
    float tm;
    {
        f32x4 m4;
#pragma unroll
        for (int r = 0; r < 4; ++r) m4[r] = fmaxf(fmaxf(s[0][r], s[1][r]), fmaxf(s[2][r], s[3][r]));
        tm = fmaxf(fmaxf(m4[0], m4[1]), fmaxf(m4[2], m4[3]));
    }
    tm = fmaxf(tm, __shfl_xor(tm, 16));
    tm = fmaxf(tm, __shfl_xor(tm, 32));
    float nm = fmaxf(rm, tm);
    float alpha = __expf(rm - nm);
    rm = nm;
    float ts = 0.f;
#pragma unroll
    for (int nt = 0; nt < 4; ++nt)
#pragma unroll
        for (int r = 0; r < 4; ++r) { float pv = __expf(s[nt][r] - nm); s[nt][r] = pv; ts += pv; }
    ts += __shfl_xor(ts, 16);
    ts += __shfl_xor(ts, 32);
    rl = rl * alpha + ts;
#pragma unroll
    for (int nt = 0; nt < 4; ++nt) y[nt] *= alpha;
    union { unsigned u[4]; bf16x8 v; } pf0, pf1;
    pf0.u[0] = cvtpk(s[0][0], s[0][1]); pf0.u[1] = cvtpk(s[0][2], s[0][3]);
    pf0.u[2] = cvtpk(s[1][0], s[1][1]); pf0.u[3] = cvtpk(s[1][2], s[1][3]);
    pf1.u[0] = cvtpk(s[2][0], s[2][1]); pf1.u[1] = cvtpk(s[2][2], s[2][3]);
    pf1.u[2] = cvtpk(s[3][0], s[3][1]); pf1.u[3] = cvtpk(s[3][2], s[3][3]);
    int s0 = g >> 1, h8 = (g & 1) * 8;
    int vo0 = lr * 128 + h8 + (((s0 + 0) ^ l7) << 4);
    int vo1 = lr * 128 + h8 + (((s0 + 2) ^ l7) << 4);
    int vo2 = lr * 128 + h8 + (((s0 + 4) ^ l7) << 4);
    int vo3 = lr * 128 + h8 + (((s0 + 6) ^ l7) << 4);
#pragma unroll
    for (int nt = 0; nt < 4; ++nt) {
        union { uint2 u2[2]; bf16x8 v; } vf;
        vf.u2[0] = *(const uint2*)(vc + nt * 2048 + vo0);
        vf.u2[1] = *(const uint2*)(vc + nt * 2048 + vo1);
        y[nt] = MFMA16(vf.v, pf0.v, y[nt]);
        union { uint2 u2[2]; bf16x8 v; } vg;
        vg.u2[0] = *(const uint2*)(vc + nt * 2048 + vo2);
        vg.u2[1] = *(const uint2*)(vc + nt * 2048 + vo3);
        y[nt] = MFMA16(vg.v, pf1.v, y[nt]);
    }
}

__device__ __forceinline__ void attn_epilogue(unsigned short* smem, unsigned short* __restrict__ Yb,
                                              f32x4 (&y)[4], float rl, int qtile,
                                              int b, int hh, int w, int lr, int g, int tid) {
    __syncthreads();
    float inv = 1.0f / rl;
    char* ep = (char*)smem;
#pragma unroll
    for (int nt = 0; nt < 4; ++nt) {
        uint2 pr;
        pr.x = cvtpk(y[nt][0] * inv, y[nt][1] * inv);
        pr.y = cvtpk(y[nt][2] * inv, y[nt][3] * inv);
        *(uint2*)(ep + (w * 16 + lr) * 144 + (nt * 16 + g * 4) * 2) = pr;
    }
    __syncthreads();
    int q = tid >> 2, dc = (tid & 3) * 16;
    uint4 u0 = *(const uint4*)(ep + q * 144 + dc * 2);
    uint4 u1 = *(const uint4*)(ep + q * 144 + dc * 2 + 16);
    size_t orow = ((size_t)(b * 1024 + qtile * 64 + q)) * 1024 + hh * 64 + dc;
    *(uint4*)(Yb + orow) = u0;
    *(uint4*)(Yb + orow + 8) = u1;
}

__global__ __launch_bounds__(256) void attn_fwd(const unsigned short* __restrict__ Qh,
                                                const unsigned short* __restrict__ Kh,
                                                const unsigned short* __restrict__ Vt,
                                                unsigned short* __restrict__ Yb) {
    __shared__ __attribute__((aligned(16))) unsigned short smem[8192];
    unsigned short* Ks = smem;
    unsigned short* Vs = smem + 4096;

    int bid = blockIdx.x;
    int lg = (bid & 7) * 128 + (bid >> 3);
    int bh = lg >> 3, p = lg & 7;
    int qa = p, qb = 15 - p;

    int tid = threadIdx.x, w = tid >> 6, l = tid & 63;
    int lr = l & 15, g = l >> 4;
    int ldsb = __builtin_amdgcn_readfirstlane(w * 512);

    size_t bh64 = (size_t)bh * 65536;
    const unsigned short* qbase = Qh + bh64 + (size_t)(w * 16 + lr) * 64 + g * 8;
    bf16x8 qA0 = ld_bf16x8(qbase + qa * 4096);
    bf16x8 qA1 = ld_bf16x8(qbase + qa * 4096 + 32);
    bf16x8 qB0 = ld_bf16x8(qbase + qb * 4096);
    bf16x8 qB1 = ld_bf16x8(qbase + qb * 4096 + 32);

    f32x4 yA[4] = {}, yB[4] = {};
    float mA = -3e38f, lA = 0.f, mB = -3e38f, lB = 0.f;

    int c0 = tid, c1 = tid + 256;
    const unsigned short* K0 = Kh + bh64 + (c0 >> 3) * 64 + ((c0 ^ (c0 >> 3)) & 7) * 8;
    const unsigned short* K1 = Kh + bh64 + (c1 >> 3) * 64 + ((c1 ^ (c1 >> 3)) & 7) * 8;
    const unsigned short* V0 = Vt + bh64 + (c0 >> 3) * 1024 + ((c0 ^ (c0 >> 3)) & 7) * 8;
    const unsigned short* V1 = Vt + bh64 + (c1 >> 3) * 1024 + ((c1 ^ (c1 >> 3)) & 7) * 8;

    for (int t = 0; t <= qb; ++t) {
        __syncthreads();
        __builtin_amdgcn_global_load_lds((const as1_u32*)(K0 + t * 4096), (as3_u32*)(Ks + ldsb), 16, 0, 0);
        __builtin_amdgcn_global_load_lds((const as1_u32*)(K1 + t * 4096), (as3_u32*)(Ks + 2048 + ldsb), 16, 0, 0);
        __builtin_amdgcn_global_load_lds((const as1_u32*)(V0 + t * 64), (as3_u32*)(Vs + ldsb), 16, 0, 0);
        __builtin_amdgcn_global_load_lds((const as1_u32*)(V1 + t * 64), (as3_u32*)(Vs + 2048 + ldsb), 16, 0, 0);
        __syncthreads();

        if (t <= qa)
            attn_tile(Ks, Vs, qA0, qA1, yA, mA, lA, lr, g, t == qa, w * 16);
        attn_tile(Ks, Vs, qB0, qB1, yB, mB, lB, lr, g, t == qb, w * 16);
    }

    int b = bh >> 4, hh = bh & 15;
    attn_epilogue(smem, Yb, yA, lA, qa, b, hh, w, lr, g, tid);
    attn_epilogue(smem, Yb, yB, lB, qb, b, hh, w, lr, g, tid);
}

// ---------------------------------------------------------------------------
extern "C" void kernel_launch(void* const* d_in, const int* in_sizes, int n_in,
                              void* d_out, int out_size, void* d_ws, size_t ws_size,
                              hipStream_t stream) {
    const float* x = (const float*)d_in[0];
    const float* ipw = (const float*)d_in[1];
    const float* ipb = (const float*)d_in[2];
    const float* opw = (const float*)d_in[3];
    const float* opb = (const float*)d_in[4];

    char* ws = (char*)d_ws;
    unsigned short* xb   = (unsigned short*)(ws);               // 16 MB
    unsigned short* wqkv = (unsigned short*)(ws + 16777216);    // 6 MB
    unsigned short* wo   = (unsigned short*)(ws + 23068672);    // 2 MB
    float* ct            = (float*)(ws + 25165824);             // 128 KB
    float* st            = (float*)(ws + 25296896);             // 128 KB
    unsigned short* qkvb = (unsigned short*)(ws + 25427968);    // 48 MB
    unsigned short* Qh   = (unsigned short*)(ws + 75759616);    // 16 MB
    unsigned short* Kh   = (unsigned short*)(ws + 92536832);    // 16 MB
    unsigned short* Vt   = (unsigned short*)(ws + 109314048);   // 16 MB
    unsigned short* yb   = (unsigned short*)(ws + 126091264);   // 16 MB

    cast_f32_bf16<<<4096, 256, 0, stream>>>(x, xb, 1048576);
    cast_f32_bf16<<<1536, 256, 0, stream>>>(ipw, wqkv, 393216);
    cast_f32_bf16<<<512, 256, 0, stream>>>(opw, wo, 131072);
    rope_table<<<128, 256, 0, stream>>>(ct, st);

    gemm1_8ph<<<384, 512, 0, stream>>>(xb, wqkv, ipb, qkvb);
    rope_reshape<<<8192, 256, 0, stream>>>(qkvb, ct, st, Qh, Kh);
    transpose_v<<<2048, 256, 0, stream>>>(qkvb, Vt);
    attn_fwd<<<1024, 256, 0, stream>>>(Qh, Kh, Vt, yb);
    gemm_bt<1024, false><<<512, 256, 0, stream>>>(yb, wo, opb, d_out, 1024);
}

// Round 5
// 265.523 us; speedup vs baseline: 1.2204x; 1.0442x over previous
//
#include <hip/hip_runtime.h>
#include <stdint.h>

// ---------------------------------------------------------------------------
// MultiheadAttention fused pipeline, bf16 MFMA compute:
//   cast(x,ipw,opw) -> bf16 ; rope tables
//   gemm1_8ph: qkv = x @ ipw^T + ipb   (256x384 tile, grid=256 = 1 exact round,
//              ring-3 LDS, counted vmcnt, setprio, vectorized epilogue)
//   rope_reshape: Q*0.125,K roped -> [B,H,T,64]   (V skipped)
//   transpose_v: qkv V-section -> Vt [B,H,64,T]
//   attn: causal flash attention, swapped-QK^T, paired q-tiles
//   gemm2: out = y @ opw^T + opb                  (fp32 out, m97 structure)
// B=8 T=1024 C=1024 H=16 hd=64
// ---------------------------------------------------------------------------

typedef __bf16 bf16x8 __attribute__((ext_vector_type(8)));
typedef float f32x4 __attribute__((ext_vector_type(4)));
typedef __attribute__((address_space(1))) unsigned int as1_u32;
typedef __attribute__((address_space(3))) unsigned int as3_u32;

#define MFMA16(a, b, c) __builtin_amdgcn_mfma_f32_16x16x32_bf16((a), (b), (c), 0, 0, 0)

static __device__ __forceinline__ unsigned short f2bf(float f) {
    union { float f; unsigned u; } x; x.f = f;
    return (unsigned short)((x.u + 0x7fffu + ((x.u >> 16) & 1u)) >> 16);
}
static __device__ __forceinline__ float bf2f(unsigned short u) {
    union { unsigned u; float f; } x; x.u = ((unsigned)u) << 16;
    return x.f;
}
static __device__ __forceinline__ bf16x8 ld_bf16x8(const void* p) {
    return *(const bf16x8*)p;
}
static __device__ __forceinline__ unsigned cvtpk(float lo, float hi) {
    unsigned r;
    asm("v_cvt_pk_bf16_f32 %0, %1, %2" : "=v"(r) : "v"(lo), "v"(hi));
    return r;
}

// ---------------- fp32 -> bf16 cast, 8 elems/thread ----------------
__global__ void cast_f32_bf16(const float* __restrict__ in,
                              unsigned short* __restrict__ out, int n8) {
    int i = blockIdx.x * blockDim.x + threadIdx.x;
    if (i >= n8) return;
    float4 a = ((const float4*)in)[2 * i];
    float4 b = ((const float4*)in)[2 * i + 1];
    union { unsigned short us[8]; uint4 v; } o;
    o.us[0] = f2bf(a.x); o.us[1] = f2bf(a.y); o.us[2] = f2bf(a.z); o.us[3] = f2bf(a.w);
    o.us[4] = f2bf(b.x); o.us[5] = f2bf(b.y); o.us[6] = f2bf(b.z); o.us[7] = f2bf(b.w);
    ((uint4*)out)[i] = o.v;
}

// ---------------- RoPE cos/sin tables [1024][32] fp32 ----------------
__global__ void rope_table(float* __restrict__ ct, float* __restrict__ st) {
    int idx = blockIdx.x * blockDim.x + threadIdx.x;
    if (idx >= 1024 * 32) return;
    int t = idx >> 5, i = idx & 31;
    float inv = powf(10000.0f, -(float)(2 * i) * (1.0f / 64.0f));
    float f = (float)t * inv;
    ct[idx] = cosf(f);
    st[idx] = sinf(f);
}

// ---------------- gemm1: 256x384 tile, grid 256 (1 exact round) ------------
// K-half = 32 cols; LDS ring-3 per matrix. Slot layout [rows][32] bf16 stored
// as [rows/2][64] row-pair interleave with slot-XOR swizzle (rule 21: inverse
// swizzle on global source, swizzle on ds_read). 8 waves = 2M x 4N, per-wave
// 128x96 out (acc 8x6). Per iter: 2 phases, each {ds_reads, stage, barrier,
// setprio{24 MFMA}, barrier}; vmcnt(5) steady-state (stage j+2 during j).
__global__ __launch_bounds__(512, 2) void gemm1_8ph(const unsigned short* __restrict__ A,
                                                    const unsigned short* __restrict__ W,
                                                    const float* __restrict__ bias,
                                                    unsigned short* __restrict__ Cout) {
    __shared__ __attribute__((aligned(16))) char lds[122880];  // A ring 48KB | B ring 72KB
    constexpr int NH = 32;  // K / 32

    int nwg = gridDim.x;  // 256
    int bid = blockIdx.x;
    int lg = (bid & 7) * (nwg >> 3) + (bid >> 3);  // XCD swizzle (256 % 8 == 0)
    int tm = lg >> 3, tn = lg & 7;
    int m0 = tm * 256, n0 = tn * 384;

    int tid = threadIdx.x;
    int w = tid >> 6, l = tid & 63;
    int lr = l & 15, g = l >> 4;
    int wm = w >> 2, wn = w & 3;
    int ldsb = __builtin_amdgcn_readfirstlane(w * 1024);  // byte, wave-uniform

    // staging: chunk c -> lds_row c>>3, stored slot c&7; source inverse-swizzled
    auto srcoff = [](int c) {
        int row = c >> 3;
        int sl = (c & 7) ^ (row & 7);       // logical slot
        int rg = (row << 1) | (sl >> 2);    // global row within tile
        int cg = (sl & 3) * 8;              // col within k-half
        return rg * 1024 + cg;              // elements (row stride K=1024)
    };
    const unsigned short* pA0 = A + (size_t)m0 * 1024 + srcoff(tid);
    const unsigned short* pA1 = A + (size_t)m0 * 1024 + srcoff(tid + 512);
    const unsigned short* pB0 = W + (size_t)n0 * 1024 + srcoff(tid);
    const unsigned short* pB1 = W + (size_t)n0 * 1024 + srcoff(tid + 512);
    const unsigned short* pB2 = W + (size_t)n0 * 1024 + srcoff(tid + 1024);

    // read bases: lane reads global row base+lr, k-chunk g*8
    int lr2 = lr >> 1;
    int sst16 = ((((lr & 1) << 2) + g) ^ lr2) << 4;
    int aBase = (wm * 64 + lr2) * 128 + sst16;  // + fm*1024 per fragment
    int bBase = (wn * 48 + lr2) * 128 + sst16;  // + fn*1024 per fragment

    f32x4 acc[8][6] = {};

    int aC = 0, aN = 16384, aP = 32768;
    int bC = 49152, bN = 73728, bP = 98304;

    // prologue: stage k-halves 0 (slots C) and 1 (slots N)
    __builtin_amdgcn_global_load_lds((const as1_u32*)(pA0), (as3_u32*)(lds + aC + ldsb), 16, 0, 0);
    __builtin_amdgcn_global_load_lds((const as1_u32*)(pA1), (as3_u32*)(lds + aC + 8192 + ldsb), 16, 0, 0);
    __builtin_amdgcn_global_load_lds((const as1_u32*)(pB0), (as3_u32*)(lds + bC + ldsb), 16, 0, 0);
    __builtin_amdgcn_global_load_lds((const as1_u32*)(pB1), (as3_u32*)(lds + bC + 8192 + ldsb), 16, 0, 0);
    __builtin_amdgcn_global_load_lds((const as1_u32*)(pB2), (as3_u32*)(lds + bC + 16384 + ldsb), 16, 0, 0);
    __builtin_amdgcn_global_load_lds((const as1_u32*)(pA0 + 32), (as3_u32*)(lds + aN + ldsb), 16, 0, 0);
    __builtin_amdgcn_global_load_lds((const as1_u32*)(pA1 + 32), (as3_u32*)(lds + aN + 8192 + ldsb), 16, 0, 0);
    __builtin_amdgcn_global_load_lds((const as1_u32*)(pB0 + 32), (as3_u32*)(lds + bN + ldsb), 16, 0, 0);
    __builtin_amdgcn_global_load_lds((const as1_u32*)(pB1 + 32), (as3_u32*)(lds + bN + 8192 + ldsb), 16, 0, 0);
    __builtin_amdgcn_global_load_lds((const as1_u32*)(pB2 + 32), (as3_u32*)(lds + bN + 16384 + ldsb), 16, 0, 0);
    asm volatile("s_waitcnt vmcnt(5)" ::: "memory");
    __builtin_amdgcn_s_barrier();

#pragma unroll
    for (int j = 0; j < NH; ++j) {
        const char* Asl = lds + aC;
        const char* Bsl = lds + bC;
        int ko = (j + 2) * 32;
        bool st = (j + 2) < NH;
        bf16x8 aa[4], bb[6];

        // ---- phase 0: bb[6] + aa low; stage A(j+2) ----
#pragma unroll
        for (int fn = 0; fn < 6; ++fn) bb[fn] = ld_bf16x8(Bsl + bBase + fn * 1024);
#pragma unroll
        for (int fm = 0; fm < 4; ++fm) aa[fm] = ld_bf16x8(Asl + aBase + fm * 1024);
        if (st) {
            __builtin_amdgcn_global_load_lds((const as1_u32*)(pA0 + ko), (as3_u32*)(lds + aP + ldsb), 16, 0, 0);
            __builtin_amdgcn_global_load_lds((const as1_u32*)(pA1 + ko), (as3_u32*)(lds + aP + 8192 + ldsb), 16, 0, 0);
        }
        __builtin_amdgcn_s_barrier();
        __builtin_amdgcn_s_setprio(1);
#pragma unroll
        for (int fm = 0; fm < 4; ++fm)
#pragma unroll
            for (int fn = 0; fn < 6; ++fn) acc[fm][fn] = MFMA16(aa[fm], bb[fn], acc[fm][fn]);
        __builtin_amdgcn_s_setprio(0);
        __builtin_amdgcn_s_barrier();

        // ---- phase 1: aa high (reuse bb); stage B(j+2) ----
#pragma unroll
        for (int fm = 0; fm < 4; ++fm) aa[fm] = ld_bf16x8(Asl + aBase + (fm + 4) * 1024);
        if (st) {
            __builtin_amdgcn_global_load_lds((const as1_u32*)(pB0 + ko), (as3_u32*)(lds + bP + ldsb), 16, 0, 0);
            __builtin_amdgcn_global_load_lds((const as1_u32*)(pB1 + ko), (as3_u32*)(lds + bP + 8192 + ldsb), 16, 0, 0);
            __builtin_amdgcn_global_load_lds((const as1_u32*)(pB2 + ko), (as3_u32*)(lds + bP + 16384 + ldsb), 16, 0, 0);
        }
        __builtin_amdgcn_s_barrier();
        __builtin_amdgcn_s_setprio(1);
#pragma unroll
        for (int fm = 0; fm < 4; ++fm)
#pragma unroll
            for (int fn = 0; fn < 6; ++fn) acc[fm + 4][fn] = MFMA16(aa[fm], bb[fn], acc[fm + 4][fn]);
        __builtin_amdgcn_s_setprio(0);
        if (st)                 asm volatile("s_waitcnt vmcnt(5)" ::: "memory");
        else if (j + 2 == NH)   asm volatile("s_waitcnt vmcnt(0)" ::: "memory");
        __builtin_amdgcn_s_barrier();

        int t = aC; aC = aN; aN = aP; aP = t;
        t = bC; bC = bN; bN = bP; bP = t;
    }

    // ---- epilogue: wave-private LDS transpose -> coalesced uint4 stores ----
    __syncthreads();
    char* ep = lds + w * 3072;  // [16 rows][192B], col-XOR swizzle by g
    float bv[6];
#pragma unroll
    for (int fn = 0; fn < 6; ++fn) bv[fn] = bias[n0 + wn * 96 + fn * 16 + lr];
#pragma unroll
    for (int fm = 0; fm < 8; ++fm) {
#pragma unroll
        for (int fn = 0; fn < 6; ++fn)
#pragma unroll
            for (int r = 0; r < 4; ++r)
                *(unsigned short*)(ep + (g * 4 + r) * 192 + (((fn * 16 + lr) * 2) ^ (g << 4))) =
                    f2bf(acc[fm][fn][r] + bv[fn]);
        asm volatile("s_waitcnt lgkmcnt(0)" ::: "memory");
        __builtin_amdgcn_sched_barrier(0);
#pragma unroll
        for (int i = 0; i < 3; ++i) {
            int c = l + 64 * i;
            int row = c / 12, ch = c - row * 12;
            int swz = (row & 12) << 2;  // ((row>>2)&3)<<4
            uint4 v = *(const uint4*)(ep + row * 192 + ((ch * 16) ^ swz));
            *(uint4*)(Cout + (size_t)(m0 + wm * 128 + fm * 16 + row) * 3072 + (n0 + wn * 96 + ch * 8)) = v;
        }
    }
}

// ---------------- bf16 GEMM (m97 128^2): C = A @ W^T + bias ----------------
template <int NC, bool OUT_BF16>
__global__ __launch_bounds__(256) void gemm_bt(const unsigned short* __restrict__ A,
                                               const unsigned short* __restrict__ W,
                                               const float* __restrict__ bias,
                                               void* __restrict__ Cout, int K) {
    __shared__ __attribute__((aligned(16))) unsigned short As[128 * 32];
    __shared__ __attribute__((aligned(16))) unsigned short Bs[128 * 32];

    constexpr int NT = NC / 128;
    int nwg = gridDim.x;
    int bid = blockIdx.x;
    int lg = (bid & 7) * (nwg >> 3) + (bid >> 3);
    int tm = lg / NT, tn = lg % NT;
    int m0 = tm * 128, n0 = tn * 128;

    int tid = threadIdx.x;
    int w = tid >> 6, l = tid & 63;
    int lr = l & 15, g = l >> 4;
    int ldsb = __builtin_amdgcn_readfirstlane(w * 512);

    int c0 = tid, c1 = tid + 256;
    const unsigned short* A0 = A + (size_t)(m0 + (c0 >> 2)) * K + (c0 & 3) * 8;
    const unsigned short* A1 = A + (size_t)(m0 + (c1 >> 2)) * K + (c1 & 3) * 8;
    const unsigned short* W0 = W + (size_t)(n0 + (c0 >> 2)) * K + (c0 & 3) * 8;
    const unsigned short* W1 = W + (size_t)(n0 + (c1 >> 2)) * K + (c1 & 3) * 8;

    f32x4 acc[4][4] = {};
    int wr = (w >> 1) * 64, wc = (w & 1) * 64;

    for (int k0 = 0; k0 < K; k0 += 32) {
        __syncthreads();
        __builtin_amdgcn_global_load_lds((const as1_u32*)(A0 + k0), (as3_u32*)(As + ldsb), 16, 0, 0);
        __builtin_amdgcn_global_load_lds((const as1_u32*)(A1 + k0), (as3_u32*)(As + 2048 + ldsb), 16, 0, 0);
        __builtin_amdgcn_global_load_lds((const as1_u32*)(W0 + k0), (as3_u32*)(Bs + ldsb), 16, 0, 0);
        __builtin_amdgcn_global_load_lds((const as1_u32*)(W1 + k0), (as3_u32*)(Bs + 2048 + ldsb), 16, 0, 0);
        __syncthreads();

        bf16x8 a[4], b[4];
#pragma unroll
        for (int i = 0; i < 4; ++i) a[i] = ld_bf16x8(As + (wr + i * 16 + lr) * 32 + g * 8);
#pragma unroll
        for (int j = 0; j < 4; ++j) b[j] = ld_bf16x8(Bs + (wc + j * 16 + lr) * 32 + g * 8);
#pragma unroll
        for (int i = 0; i < 4; ++i)
#pragma unroll
            for (int j = 0; j < 4; ++j) acc[i][j] = MFMA16(a[i], b[j], acc[i][j]);
    }

    int g4 = g * 4;
#pragma unroll
    for (int j = 0; j < 4; ++j) {
        int col = n0 + wc + j * 16 + lr;
        float bv = bias[col];
#pragma unroll
        for (int i = 0; i < 4; ++i) {
#pragma unroll
            for (int r = 0; r < 4; ++r) {
                int row = m0 + wr + i * 16 + g4 + r;
                float v = acc[i][j][r] + bv;
                if (OUT_BF16)
                    ((unsigned short*)Cout)[(size_t)row * NC + col] = f2bf(v);
                else
                    ((float*)Cout)[(size_t)row * NC + col] = v;
            }
        }
    }
}

// ---------------- RoPE + reshape Q,K only -> [B,H,T,64]; Q scaled 0.125 ----
__global__ void rope_reshape(const unsigned short* __restrict__ qkv,
                             const float* __restrict__ ct, const float* __restrict__ st,
                             unsigned short* __restrict__ Qh,
                             unsigned short* __restrict__ Kh) {
    int idx = blockIdx.x * blockDim.x + threadIdx.x;
    if (idx >= 8192 * 256) return;
    int row = idx >> 8;
    int col = (idx & 255) * 8;
    int sec = col >> 10;
    int wi = col & 1023;
    int h = wi >> 6, d = wi & 63;
    int t = row & 1023;

    uint4 raw = *(const uint4*)(qkv + (size_t)row * 3072 + col);
    size_t obase = ((size_t)((row >> 10) * 16 + h) * 1024 + t) * 64 + d;

    union { uint4 v; unsigned short us[8]; } u; u.v = raw;
    float x[8];
#pragma unroll
    for (int i = 0; i < 8; ++i) x[i] = bf2f(u.us[i]);
    float scale = (sec == 0) ? 0.125f : 1.0f;
    union { uint4 v; unsigned short us[8]; } o;
#pragma unroll
    for (int p = 0; p < 4; ++p) {
        int fi = t * 32 + (d >> 1) + p;
        float c = ct[fi], s = st[fi];
        float e0 = (x[2 * p] * c - x[2 * p + 1] * s) * scale;
        float e1 = (x[2 * p + 1] * c + x[2 * p] * s) * scale;
        o.us[2 * p] = f2bf(e0);
        o.us[2 * p + 1] = f2bf(e1);
    }
    unsigned short* dst = (sec == 0) ? Qh : Kh;
    *(uint4*)(dst + obase) = o.v;
}

// ---------------- V transpose: qkv[:,2048+h*64+d] -> Vt[b,h,d,t] -----------
__global__ __launch_bounds__(256) void transpose_v(const unsigned short* __restrict__ qkv,
                                                   unsigned short* __restrict__ Vt) {
    __shared__ unsigned short Ts[64 * 67];
    int bid = blockIdx.x;
    int bh = bid >> 4, tt = bid & 15;
    int b = bh >> 4, h = bh & 15;
    int t0 = tt * 64;
    int tid = threadIdx.x;
#pragma unroll
    for (int cc = 0; cc < 2; ++cc) {
        int c = tid + cc * 256;
        int trow = c >> 3, d8 = (c & 7) * 8;
        uint4 v = *(const uint4*)(qkv + (size_t)(b * 1024 + t0 + trow) * 3072 + 2048 + h * 64 + d8);
        union { uint4 v; unsigned short us[8]; } u; u.v = v;
#pragma unroll
        for (int i = 0; i < 8; ++i) Ts[trow * 67 + d8 + i] = u.us[i];
    }
    __syncthreads();
#pragma unroll
    for (int cc = 0; cc < 2; ++cc) {
        int c = tid + cc * 256;
        int drow = c >> 3, t8 = (c & 7) * 8;
        union { uint4 v; unsigned short us[8]; } u;
#pragma unroll
        for (int i = 0; i < 8; ++i) u.us[i] = Ts[(t8 + i) * 67 + drow];
        *(uint4*)(Vt + (size_t)bh * 65536 + (size_t)drow * 1024 + t0 + t8) = u.v;
    }
}

// ---------------- causal flash attention (swapped QK^T, paired q-tiles) ----
__device__ __forceinline__ void attn_tile(const unsigned short* Ks, const unsigned short* Vs,
                                          bf16x8 q0f, bf16x8 q1f, f32x4 (&y)[4],
                                          float& rm, float& rl,
                                          int lr, int g, bool diag, int wq) {
    const char* kc = (const char*)Ks;
    const char* vc = (const char*)Vs;
    int l7 = lr & 7;
    int kof0 = lr * 128 + ((g ^ l7) << 4);
    int kof1 = lr * 128 + (((g + 4) ^ l7) << 4);
    f32x4 s[4];
#pragma unroll
    for (int nt = 0; nt < 4; ++nt) {
        bf16x8 kf0 = ld_bf16x8(kc + nt * 2048 + kof0);
        bf16x8 kf1 = ld_bf16x8(kc + nt * 2048 + kof1);
        f32x4 z = {};
        z = MFMA16(kf0, q0f, z);
        z = MFMA16(kf1, q1f, z);
        s[nt] = z;
    }
    if (diag) {
#pragma unroll
        for (int nt = 0; nt < 4; ++nt)
#pragma unroll
            for (int r = 0; r < 4; ++r)
                if (nt * 16 + g * 4 + r > wq + lr) s[nt][r] = -3e38f;
    }
    float tm;
    {
        f32x4 m4;
#pragma unroll
        for (int r = 0; r < 4; ++r) m4[r] = fmaxf(fmaxf(s[0][r], s[1][r]), fmaxf(s[2][r], s[3][r]));
        tm = fmaxf(fmaxf(m4[0], m4[1]), fmaxf(m4[2], m4[3]));
    }
    tm = fmaxf(tm, __shfl_xor(tm, 16));
    tm = fmaxf(tm, __shfl_xor(tm, 32));
    float nm = fmaxf(rm, tm);
    float alpha = __expf(rm - nm);
    rm = nm;
    float ts = 0.f;
#pragma unroll
    for (int nt = 0; nt < 4; ++nt)
#pragma unroll
        for (int r = 0; r < 4; ++r) { float pv = __expf(s[nt][r] - nm); s[nt][r] = pv; ts += pv; }
    ts += __shfl_xor(ts, 16);
    ts += __shfl_xor(ts, 32);
    rl = rl * alpha + ts;
#pragma unroll
    for (int nt = 0; nt < 4; ++nt) y[nt] *= alpha;
    union { unsigned u[4]; bf16x8 v; } pf0, pf1;
    pf0.u[0] = cvtpk(s[0][0], s[0][1]); pf0.u[1] = cvtpk(s[0][2], s[0][3]);
    pf0.u[2] = cvtpk(s[1][0], s[1][1]); pf0.u[3] = cvtpk(s[1][2], s[1][3]);
    pf1.u[0] = cvtpk(s[2][0], s[2][1]); pf1.u[1] = cvtpk(s[2][2], s[2][3]);
    pf1.u[2] = cvtpk(s[3][0], s[3][1]); pf1.u[3] = cvtpk(s[3][2], s[3][3]);
    int s0 = g >> 1, h8 = (g & 1) * 8;
    int vo0 = lr * 128 + h8 + (((s0 + 0) ^ l7) << 4);
    int vo1 = lr * 128 + h8 + (((s0 + 2) ^ l7) << 4);
    int vo2 = lr * 128 + h8 + (((s0 + 4) ^ l7) << 4);
    int vo3 = lr * 128 + h8 + (((s0 + 6) ^ l7) << 4);
#pragma unroll
    for (int nt = 0; nt < 4; ++nt) {
        union { uint2 u2[2]; bf16x8 v; } vf;
        vf.u2[0] = *(const uint2*)(vc + nt * 2048 + vo0);
        vf.u2[1] = *(const uint2*)(vc + nt * 2048 + vo1);
        y[nt] = MFMA16(vf.v, pf0.v, y[nt]);
        union { uint2 u2[2]; bf16x8 v; } vg;
        vg.u2[0] = *(const uint2*)(vc + nt * 2048 + vo2);
        vg.u2[1] = *(const uint2*)(vc + nt * 2048 + vo3);
        y[nt] = MFMA16(vg.v, pf1.v, y[nt]);
    }
}

__device__ __forceinline__ void attn_epilogue(unsigned short* smem, unsigned short* __restrict__ Yb,
                                              f32x4 (&y)[4], float rl, int qtile,
                                              int b, int hh, int w, int lr, int g, int tid) {
    __syncthreads();
    float inv = 1.0f / rl;
    char* ep = (char*)smem;
#pragma unroll
    for (int nt = 0; nt < 4; ++nt) {
        uint2 pr;
        pr.x = cvtpk(y[nt][0] * inv, y[nt][1] * inv);
        pr.y = cvtpk(y[nt][2] * inv, y[nt][3] * inv);
        *(uint2*)(ep + (w * 16 + lr) * 144 + (nt * 16 + g * 4) * 2) = pr;
    }
    __syncthreads();
    int q = tid >> 2, dc = (tid & 3) * 16;
    uint4 u0 = *(const uint4*)(ep + q * 144 + dc * 2);
    uint4 u1 = *(const uint4*)(ep + q * 144 + dc * 2 + 16);
    size_t orow = ((size_t)(b * 1024 + qtile * 64 + q)) * 1024 + hh * 64 + dc;
    *(uint4*)(Yb + orow) = u0;
    *(uint4*)(Yb + orow + 8) = u1;
}

__global__ __launch_bounds__(256) void attn_fwd(const unsigned short* __restrict__ Qh,
                                                const unsigned short* __restrict__ Kh,
                                                const unsigned short* __restrict__ Vt,
                                                unsigned short* __restrict__ Yb) {
    __shared__ __attribute__((aligned(16))) unsigned short smem[8192];
    unsigned short* Ks = smem;
    unsigned short* Vs = smem + 4096;

    int bid = blockIdx.x;
    int lg = (bid & 7) * 128 + (bid >> 3);
    int bh = lg >> 3, p = lg & 7;
    int qa = p, qb = 15 - p;

    int tid = threadIdx.x, w = tid >> 6, l = tid & 63;
    int lr = l & 15, g = l >> 4;
    int ldsb = __builtin_amdgcn_readfirstlane(w * 512);

    size_t bh64 = (size_t)bh * 65536;
    const unsigned short* qbase = Qh + bh64 + (size_t)(w * 16 + lr) * 64 + g * 8;
    bf16x8 qA0 = ld_bf16x8(qbase + qa * 4096);
    bf16x8 qA1 = ld_bf16x8(qbase + qa * 4096 + 32);
    bf16x8 qB0 = ld_bf16x8(qbase + qb * 4096);
    bf16x8 qB1 = ld_bf16x8(qbase + qb * 4096 + 32);

    f32x4 yA[4] = {}, yB[4] = {};
    float mA = -3e38f, lA = 0.f, mB = -3e38f, lB = 0.f;

    int c0 = tid, c1 = tid + 256;
    const unsigned short* K0 = Kh + bh64 + (c0 >> 3) * 64 + ((c0 ^ (c0 >> 3)) & 7) * 8;
    const unsigned short* K1 = Kh + bh64 + (c1 >> 3) * 64 + ((c1 ^ (c1 >> 3)) & 7) * 8;
    const unsigned short* V0 = Vt + bh64 + (c0 >> 3) * 1024 + ((c0 ^ (c0 >> 3)) & 7) * 8;
    const unsigned short* V1 = Vt + bh64 + (c1 >> 3) * 1024 + ((c1 ^ (c1 >> 3)) & 7) * 8;

    for (int t = 0; t <= qb; ++t) {
        __syncthreads();
        __builtin_amdgcn_global_load_lds((const as1_u32*)(K0 + t * 4096), (as3_u32*)(Ks + ldsb), 16, 0, 0);
        __builtin_amdgcn_global_load_lds((const as1_u32*)(K1 + t * 4096), (as3_u32*)(Ks + 2048 + ldsb), 16, 0, 0);
        __builtin_amdgcn_global_load_lds((const as1_u32*)(V0 + t * 64), (as3_u32*)(Vs + ldsb), 16, 0, 0);
        __builtin_amdgcn_global_load_lds((const as1_u32*)(V1 + t * 64), (as3_u32*)(Vs + 2048 + ldsb), 16, 0, 0);
        __syncthreads();

        if (t <= qa)
            attn_tile(Ks, Vs, qA0, qA1, yA, mA, lA, lr, g, t == qa, w * 16);
        attn_tile(Ks, Vs, qB0, qB1, yB, mB, lB, lr, g, t == qb, w * 16);
    }

    int b = bh >> 4, hh = bh & 15;
    attn_epilogue(smem, Yb, yA, lA, qa, b, hh, w, lr, g, tid);
    attn_epilogue(smem, Yb, yB, lB, qb, b, hh, w, lr, g, tid);
}

// ---------------------------------------------------------------------------
extern "C" void kernel_launch(void* const* d_in, const int* in_sizes, int n_in,
                              void* d_out, int out_size, void* d_ws, size_t ws_size,
                              hipStream_t stream) {
    const float* x = (const float*)d_in[0];
    const float* ipw = (const float*)d_in[1];
    const float* ipb = (const float*)d_in[2];
    const float* opw = (const float*)d_in[3];
    const float* opb = (const float*)d_in[4];

    char* ws = (char*)d_ws;
    unsigned short* xb   = (unsigned short*)(ws);               // 16 MB
    unsigned short* wqkv = (unsigned short*)(ws + 16777216);    // 6 MB
    unsigned short* wo   = (unsigned short*)(ws + 23068672);    // 2 MB
    float* ct            = (float*)(ws + 25165824);             // 128 KB
    float* st            = (float*)(ws + 25296896);             // 128 KB
    unsigned short* qkvb = (unsigned short*)(ws + 25427968);    // 48 MB
    unsigned short* Qh   = (unsigned short*)(ws + 75759616);    // 16 MB
    unsigned short* Kh   = (unsigned short*)(ws + 92536832);    // 16 MB
    unsigned short* Vt   = (unsigned short*)(ws + 109314048);   // 16 MB
    unsigned short* yb   = (unsigned short*)(ws + 126091264);   // 16 MB

    cast_f32_bf16<<<4096, 256, 0, stream>>>(x, xb, 1048576);
    cast_f32_bf16<<<1536, 256, 0, stream>>>(ipw, wqkv, 393216);
    cast_f32_bf16<<<512, 256, 0, stream>>>(opw, wo, 131072);
    rope_table<<<128, 256, 0, stream>>>(ct, st);

    gemm1_8ph<<<256, 512, 0, stream>>>(xb, wqkv, ipb, qkvb);
    rope_reshape<<<8192, 256, 0, stream>>>(qkvb, ct, st, Qh, Kh);
    transpose_v<<<2048, 256, 0, stream>>>(qkvb, Vt);
    attn_fwd<<<1024, 256, 0, stream>>>(Qh, Kh, Vt, yb);
    gemm_bt<1024, false><<<512, 256, 0, stream>>>(yb, wo, opb, d_out, 1024);
}

// Round 6
// 259.485 us; speedup vs baseline: 1.2488x; 1.0233x over previous
//
#include <hip/hip_runtime.h>
#include <stdint.h>

// ---------------------------------------------------------------------------
// MultiheadAttention fused pipeline, bf16 MFMA compute:
//   cast(x,ipw,opw) -> bf16 ; rope tables
//   gemm1_p: qkv = x @ ipw^T + ipb   (256x192 tile, grid 512 = 2 exact rounds,
//            single-barrier register-pipelined loop, ring-3 LDS, counted vmcnt)
//   rope_reshape: Q*0.125,K roped -> [B,H,T,64]
//   transpose_v: qkv V-section -> Vt [B,H,64,T]
//   attn: causal flash attention, swapped-QK^T, paired q-tiles
//   gemm2_p: out = y @ opw^T + opb   (256x128 tile, grid 256, same pipeline)
// B=8 T=1024 C=1024 H=16 hd=64
// ---------------------------------------------------------------------------

typedef __bf16 bf16x8 __attribute__((ext_vector_type(8)));
typedef float f32x4 __attribute__((ext_vector_type(4)));
typedef __attribute__((address_space(1))) unsigned int as1_u32;
typedef __attribute__((address_space(3))) unsigned int as3_u32;

#define MFMA16(a, b, c) __builtin_amdgcn_mfma_f32_16x16x32_bf16((a), (b), (c), 0, 0, 0)
#define GLDS(src, dst) __builtin_amdgcn_global_load_lds((const as1_u32*)(src), (as3_u32*)(dst), 16, 0, 0)

static __device__ __forceinline__ unsigned short f2bf(float f) {
    union { float f; unsigned u; } x; x.f = f;
    return (unsigned short)((x.u + 0x7fffu + ((x.u >> 16) & 1u)) >> 16);
}
static __device__ __forceinline__ float bf2f(unsigned short u) {
    union { unsigned u; float f; } x; x.u = ((unsigned)u) << 16;
    return x.f;
}
static __device__ __forceinline__ bf16x8 ld_bf16x8(const void* p) {
    return *(const bf16x8*)p;
}
static __device__ __forceinline__ unsigned cvtpk(float lo, float hi) {
    unsigned r;
    asm("v_cvt_pk_bf16_f32 %0, %1, %2" : "=v"(r) : "v"(lo), "v"(hi));
    return r;
}

// ---------------- fp32 -> bf16 cast, 8 elems/thread ----------------
__global__ void cast_f32_bf16(const float* __restrict__ in,
                              unsigned short* __restrict__ out, int n8) {
    int i = blockIdx.x * blockDim.x + threadIdx.x;
    if (i >= n8) return;
    float4 a = ((const float4*)in)[2 * i];
    float4 b = ((const float4*)in)[2 * i + 1];
    union { unsigned short us[8]; uint4 v; } o;
    o.us[0] = f2bf(a.x); o.us[1] = f2bf(a.y); o.us[2] = f2bf(a.z); o.us[3] = f2bf(a.w);
    o.us[4] = f2bf(b.x); o.us[5] = f2bf(b.y); o.us[6] = f2bf(b.z); o.us[7] = f2bf(b.w);
    ((uint4*)out)[i] = o.v;
}

// ---------------- RoPE cos/sin tables [1024][32] fp32 ----------------
__global__ void rope_table(float* __restrict__ ct, float* __restrict__ st) {
    int idx = blockIdx.x * blockDim.x + threadIdx.x;
    if (idx >= 1024 * 32) return;
    int t = idx >> 5, i = idx & 31;
    float inv = powf(10000.0f, -(float)(2 * i) * (1.0f / 64.0f));
    float f = (float)t * inv;
    ct[idx] = cosf(f);
    st[idx] = sinf(f);
}

// srcoff: staging chunk c -> inverse-swizzled global element offset (stride 1024)
// lds layout per slot: [rows/2][64] bf16, stored slot (c&7) = logical ^ (lds_row&7)
static __device__ __forceinline__ int srcoff(int c) {
    int row = c >> 3;
    int sl = (c & 7) ^ (row & 7);
    return ((row << 1) | (sl >> 2)) * 1024 + (sl & 3) * 8;
}

// ---------------- gemm1: 256x192 tile, single-barrier pipelined ------------
// 8 waves 4M x 2N (per-wave 64x96, acc 4x6). Ring-3 LDS slots (A 16KB, B 12KB).
// Per iter j: {ds_read frags(j+1); stage(j+3)->slot j%3; MFMA(j) x24 [setprio];
// lgkmcnt(0); vmcnt(4); s_barrier}. Reads overlap MFMA via register dbuf.
__global__ __launch_bounds__(512, 2) void gemm1_p(const unsigned short* __restrict__ A,
                                                  const unsigned short* __restrict__ W,
                                                  const float* __restrict__ bias,
                                                  unsigned short* __restrict__ Cout) {
    __shared__ __attribute__((aligned(16))) char lds[86016];  // A 3x16KB | B 3x12KB

    int nwg = gridDim.x;  // 512
    int bid = blockIdx.x;
    int lg = (bid & 7) * (nwg >> 3) + (bid >> 3);
    int tm = lg >> 4, tn = lg & 15;  // 32 x 16
    int m0 = tm * 256, n0 = tn * 192;

    int tid = threadIdx.x, w = tid >> 6, l = tid & 63;
    int lr = l & 15, g = l >> 4, lr2 = lr >> 1;
    int wm = w >> 1, wn = w & 1;
    int ldsbA = __builtin_amdgcn_readfirstlane(w * 1024);
    int ldsbB1 = __builtin_amdgcn_readfirstlane(w * 512) + 8192;

    const unsigned short* pA0 = A + (size_t)m0 * 1024 + srcoff(tid);
    const unsigned short* pA1 = A + (size_t)m0 * 1024 + srcoff(tid + 512);
    const unsigned short* pB0 = W + (size_t)n0 * 1024 + srcoff(tid);
    const unsigned short* pB1 = W + (size_t)n0 * 1024 + srcoff(512 + w * 32 + (l & 31));

    int sst16 = ((((lr & 1) << 2) + g) ^ lr2) << 4;
    int aBase = (wm * 32 + lr2) * 128 + sst16;
    int bBase = (wn * 48 + lr2) * 128 + sst16;

    f32x4 acc[4][6] = {};
    bf16x8 af[2][4], bf[2][6];

    // prologue: stage k-halves 0,1,2 -> slots 0,1,2 (12 loads)
#pragma unroll
    for (int s = 0; s < 3; ++s) {
        char* Ad = lds + s * 16384;
        char* Bd = lds + 49152 + s * 12288;
        GLDS(pA0 + s * 32, Ad + ldsbA);
        GLDS(pA1 + s * 32, Ad + 8192 + ldsbA);
        GLDS(pB0 + s * 32, Bd + ldsbA);
        if (l < 32) GLDS(pB1 + s * 32, Bd + ldsbB1);
    }
    asm volatile("s_waitcnt vmcnt(4)" ::: "memory");  // halves 0,1 landed
    __builtin_amdgcn_s_barrier();
    __builtin_amdgcn_sched_barrier(0);
    {   // reads(0) -> buf 0
        const char* As_ = lds;
        const char* Bs_ = lds + 49152;
#pragma unroll
        for (int fm = 0; fm < 4; ++fm) af[0][fm] = ld_bf16x8(As_ + aBase + fm * 1024);
#pragma unroll
        for (int fn = 0; fn < 6; ++fn) bf[0][fn] = ld_bf16x8(Bs_ + bBase + fn * 1024);
    }
    asm volatile("s_waitcnt lgkmcnt(0)" ::: "memory");
    __builtin_amdgcn_sched_barrier(0);

#pragma unroll
    for (int j = 0; j < 32; ++j) {
        int cur = j & 1, nxt = cur ^ 1;
        if (j < 31) {  // reads(j+1) from slot (j+1)%3 -> buf nxt
            const char* As_ = lds + ((j + 1) % 3) * 16384;
            const char* Bs_ = lds + 49152 + ((j + 1) % 3) * 12288;
#pragma unroll
            for (int fm = 0; fm < 4; ++fm) af[nxt][fm] = ld_bf16x8(As_ + aBase + fm * 1024);
#pragma unroll
            for (int fn = 0; fn < 6; ++fn) bf[nxt][fn] = ld_bf16x8(Bs_ + bBase + fn * 1024);
        }
        if (j + 3 < 32) {  // stage k-half j+3 -> slot j%3 (read j drained+barrier'd)
            int ko = (j + 3) * 32;
            char* Ad = lds + (j % 3) * 16384;
            char* Bd = lds + 49152 + (j % 3) * 12288;
            GLDS(pA0 + ko, Ad + ldsbA);
            GLDS(pA1 + ko, Ad + 8192 + ldsbA);
            GLDS(pB0 + ko, Bd + ldsbA);
            if (l < 32) GLDS(pB1 + ko, Bd + ldsbB1);
        }
        __builtin_amdgcn_s_setprio(1);
#pragma unroll
        for (int fm = 0; fm < 4; ++fm)
#pragma unroll
            for (int fn = 0; fn < 6; ++fn) acc[fm][fn] = MFMA16(af[cur][fm], bf[cur][fn], acc[fm][fn]);
        __builtin_amdgcn_s_setprio(0);
        asm volatile("s_waitcnt lgkmcnt(0)" ::: "memory");
        __builtin_amdgcn_sched_barrier(0);
        if (j <= 28) asm volatile("s_waitcnt vmcnt(4)" ::: "memory");  // (j+2) landed
        else         asm volatile("s_waitcnt vmcnt(0)" ::: "memory");
        __builtin_amdgcn_s_barrier();
        __builtin_amdgcn_sched_barrier(0);
    }

    // epilogue: wave-private LDS stripe [16][192B] -> coalesced uint4 stores
    char* ep = lds + w * 3072;
    float bv[6];
#pragma unroll
    for (int fn = 0; fn < 6; ++fn) bv[fn] = bias[n0 + wn * 96 + fn * 16 + lr];
#pragma unroll
    for (int fm = 0; fm < 4; ++fm) {
#pragma unroll
        for (int fn = 0; fn < 6; ++fn)
#pragma unroll
            for (int r = 0; r < 4; ++r)
                *(unsigned short*)(ep + (g * 4 + r) * 192 + (((fn * 16 + lr) * 2) ^ (g << 4))) =
                    f2bf(acc[fm][fn][r] + bv[fn]);
        asm volatile("s_waitcnt lgkmcnt(0)" ::: "memory");
        __builtin_amdgcn_sched_barrier(0);
#pragma unroll
        for (int i = 0; i < 3; ++i) {
            int c = l + 64 * i;
            int row = c / 12, ch = c - row * 12;
            int swz = (row & 12) << 2;
            uint4 v = *(const uint4*)(ep + row * 192 + ((ch * 16) ^ swz));
            *(uint4*)(Cout + (size_t)(m0 + wm * 64 + fm * 16 + row) * 3072 + (n0 + wn * 96 + ch * 8)) = v;
        }
    }
}

// ---------------- gemm2: 256x128 tile, same pipeline, fp32+bias out --------
__global__ __launch_bounds__(512, 2) void gemm2_p(const unsigned short* __restrict__ A,
                                                  const unsigned short* __restrict__ W,
                                                  const float* __restrict__ bias,
                                                  float* __restrict__ Cout) {
    __shared__ __attribute__((aligned(16))) char lds[73728];  // A 3x16KB | B 3x8KB

    int nwg = gridDim.x;  // 256
    int bid = blockIdx.x;
    int lg = (bid & 7) * (nwg >> 3) + (bid >> 3);
    int tm = lg >> 3, tn = lg & 7;  // 32 x 8
    int m0 = tm * 256, n0 = tn * 128;

    int tid = threadIdx.x, w = tid >> 6, l = tid & 63;
    int lr = l & 15, g = l >> 4, lr2 = lr >> 1;
    int wm = w >> 1, wn = w & 1;
    int ldsbA = __builtin_amdgcn_readfirstlane(w * 1024);

    const unsigned short* pA0 = A + (size_t)m0 * 1024 + srcoff(tid);
    const unsigned short* pA1 = A + (size_t)m0 * 1024 + srcoff(tid + 512);
    const unsigned short* pB0 = W + (size_t)n0 * 1024 + srcoff(tid);

    int sst16 = ((((lr & 1) << 2) + g) ^ lr2) << 4;
    int aBase = (wm * 32 + lr2) * 128 + sst16;
    int bBase = (wn * 32 + lr2) * 128 + sst16;

    f32x4 acc[4][4] = {};
    bf16x8 af[2][4], bf[2][4];

#pragma unroll
    for (int s = 0; s < 3; ++s) {
        char* Ad = lds + s * 16384;
        char* Bd = lds + 49152 + s * 8192;
        GLDS(pA0 + s * 32, Ad + ldsbA);
        GLDS(pA1 + s * 32, Ad + 8192 + ldsbA);
        GLDS(pB0 + s * 32, Bd + ldsbA);
    }
    asm volatile("s_waitcnt vmcnt(3)" ::: "memory");
    __builtin_amdgcn_s_barrier();
    __builtin_amdgcn_sched_barrier(0);
    {
        const char* As_ = lds;
        const char* Bs_ = lds + 49152;
#pragma unroll
        for (int fm = 0; fm < 4; ++fm) af[0][fm] = ld_bf16x8(As_ + aBase + fm * 1024);
#pragma unroll
        for (int fn = 0; fn < 4; ++fn) bf[0][fn] = ld_bf16x8(Bs_ + bBase + fn * 1024);
    }
    asm volatile("s_waitcnt lgkmcnt(0)" ::: "memory");
    __builtin_amdgcn_sched_barrier(0);

#pragma unroll
    for (int j = 0; j < 32; ++j) {
        int cur = j & 1, nxt = cur ^ 1;
        if (j < 31) {
            const char* As_ = lds + ((j + 1) % 3) * 16384;
            const char* Bs_ = lds + 49152 + ((j + 1) % 3) * 8192;
#pragma unroll
            for (int fm = 0; fm < 4; ++fm) af[nxt][fm] = ld_bf16x8(As_ + aBase + fm * 1024);
#pragma unroll
            for (int fn = 0; fn < 4; ++fn) bf[nxt][fn] = ld_bf16x8(Bs_ + bBase + fn * 1024);
        }
        if (j + 3 < 32) {
            int ko = (j + 3) * 32;
            char* Ad = lds + (j % 3) * 16384;
            char* Bd = lds + 49152 + (j % 3) * 8192;
            GLDS(pA0 + ko, Ad + ldsbA);
            GLDS(pA1 + ko, Ad + 8192 + ldsbA);
            GLDS(pB0 + ko, Bd + ldsbA);
        }
        __builtin_amdgcn_s_setprio(1);
#pragma unroll
        for (int fm = 0; fm < 4; ++fm)
#pragma unroll
            for (int fn = 0; fn < 4; ++fn) acc[fm][fn] = MFMA16(af[cur][fm], bf[cur][fn], acc[fm][fn]);
        __builtin_amdgcn_s_setprio(0);
        asm volatile("s_waitcnt lgkmcnt(0)" ::: "memory");
        __builtin_amdgcn_sched_barrier(0);
        if (j <= 28) asm volatile("s_waitcnt vmcnt(3)" ::: "memory");
        else         asm volatile("s_waitcnt vmcnt(0)" ::: "memory");
        __builtin_amdgcn_s_barrier();
        __builtin_amdgcn_sched_barrier(0);
    }

    // epilogue: fp32 + bias direct (16-lane row segments = 64B stores)
#pragma unroll
    for (int fn = 0; fn < 4; ++fn) {
        int col = n0 + wn * 64 + fn * 16 + lr;
        float bv = bias[col];
#pragma unroll
        for (int fm = 0; fm < 4; ++fm) {
            int row = m0 + wm * 64 + fm * 16 + g * 4;
#pragma unroll
            for (int r = 0; r < 4; ++r)
                Cout[(size_t)(row + r) * 1024 + col] = acc[fm][fn][r] + bv;
        }
    }
}

// ---------------- RoPE + reshape Q,K only -> [B,H,T,64]; Q scaled 0.125 ----
__global__ void rope_reshape(const unsigned short* __restrict__ qkv,
                             const float* __restrict__ ct, const float* __restrict__ st,
                             unsigned short* __restrict__ Qh,
                             unsigned short* __restrict__ Kh) {
    int idx = blockIdx.x * blockDim.x + threadIdx.x;
    if (idx >= 8192 * 256) return;
    int row = idx >> 8;
    int col = (idx & 255) * 8;
    int sec = col >> 10;
    int wi = col & 1023;
    int h = wi >> 6, d = wi & 63;
    int t = row & 1023;

    uint4 raw = *(const uint4*)(qkv + (size_t)row * 3072 + col);
    size_t obase = ((size_t)((row >> 10) * 16 + h) * 1024 + t) * 64 + d;

    union { uint4 v; unsigned short us[8]; } u; u.v = raw;
    float x[8];
#pragma unroll
    for (int i = 0; i < 8; ++i) x[i] = bf2f(u.us[i]);
    float scale = (sec == 0) ? 0.125f : 1.0f;
    union { uint4 v; unsigned short us[8]; } o;
#pragma unroll
    for (int p = 0; p < 4; ++p) {
        int fi = t * 32 + (d >> 1) + p;
        float c = ct[fi], s = st[fi];
        float e0 = (x[2 * p] * c - x[2 * p + 1] * s) * scale;
        float e1 = (x[2 * p + 1] * c + x[2 * p] * s) * scale;
        o.us[2 * p] = f2bf(e0);
        o.us[2 * p + 1] = f2bf(e1);
    }
    unsigned short* dst = (sec == 0) ? Qh : Kh;
    *(uint4*)(dst + obase) = o.v;
}

// ---------------- V transpose: qkv[:,2048+h*64+d] -> Vt[b,h,d,t] -----------
__global__ __launch_bounds__(256) void transpose_v(const unsigned short* __restrict__ qkv,
                                                   unsigned short* __restrict__ Vt) {
    __shared__ unsigned short Ts[64 * 67];
    int bid = blockIdx.x;
    int bh = bid >> 4, tt = bid & 15;
    int b = bh >> 4, h = bh & 15;
    int t0 = tt * 64;
    int tid = threadIdx.x;
#pragma unroll
    for (int cc = 0; cc < 2; ++cc) {
        int c = tid + cc * 256;
        int trow = c >> 3, d8 = (c & 7) * 8;
        uint4 v = *(const uint4*)(qkv + (size_t)(b * 1024 + t0 + trow) * 3072 + 2048 + h * 64 + d8);
        union { uint4 v; unsigned short us[8]; } u; u.v = v;
#pragma unroll
        for (int i = 0; i < 8; ++i) Ts[trow * 67 + d8 + i] = u.us[i];
    }
    __syncthreads();
#pragma unroll
    for (int cc = 0; cc < 2; ++cc) {
        int c = tid + cc * 256;
        int drow = c >> 3, t8 = (c & 7) * 8;
        union { uint4 v; unsigned short us[8]; } u;
#pragma unroll
        for (int i = 0; i < 8; ++i) u.us[i] = Ts[(t8 + i) * 67 + drow];
        *(uint4*)(Vt + (size_t)bh * 65536 + (size_t)drow * 1024 + t0 + t8) = u.v;
    }
}

// ---------------- causal flash attention (swapped QK^T, paired q-tiles) ----
__device__ __forceinline__ void attn_tile(const unsigned short* Ks, const unsigned short* Vs,
                                          bf16x8 q0f, bf16x8 q1f, f32x4 (&y)[4],
                                          float& rm, float& rl,
                                          int lr, int g, bool diag, int wq) {
    const char* kc = (const char*)Ks;
    const char* vc = (const char*)Vs;
    int l7 = lr & 7;
    int kof0 = lr * 128 + ((g ^ l7) << 4);
    int kof1 = lr * 128 + (((g + 4) ^ l7) << 4);
    f32x4 s[4];
#pragma unroll
    for (int nt = 0; nt < 4; ++nt) {
        bf16x8 kf0 = ld_bf16x8(kc + nt * 2048 + kof0);
        bf16x8 kf1 = ld_bf16x8(kc + nt * 2048 + kof1);
        f32x4 z = {};
        z = MFMA16(kf0, q0f, z);
        z = MFMA16(kf1, q1f, z);
        s[nt] = z;
    }
    if (diag) {
#pragma unroll
        for (int nt = 0; nt < 4; ++nt)
#pragma unroll
            for (int r = 0; r < 4; ++r)
                if (nt * 16 + g * 4 + r > wq + lr) s[nt][r] = -3e38f;
    }
    float tm;
    {
        f32x4 m4;
#pragma unroll
        for (int r = 0; r < 4; ++r) m4[r] = fmaxf(fmaxf(s[0][r], s[1][r]), fmaxf(s[2][r], s[3][r]));
        tm = fmaxf(fmaxf(m4[0], m4[1]), fmaxf(m4[2], m4[3]));
    }
    tm = fmaxf(tm, __shfl_xor(tm, 16));
    tm = fmaxf(tm, __shfl_xor(tm, 32));
    float nm = fmaxf(rm, tm);
    float alpha = __expf(rm - nm);
    rm = nm;
    float ts = 0.f;
#pragma unroll
    for (int nt = 0; nt < 4; ++nt)
#pragma unroll
        for (int r = 0; r < 4; ++r) { float pv = __expf(s[nt][r] - nm); s[nt][r] = pv; ts += pv; }
    ts += __shfl_xor(ts, 16);
    ts += __shfl_xor(ts, 32);
    rl = rl * alpha + ts;
#pragma unroll
    for (int nt = 0; nt < 4; ++nt) y[nt] *= alpha;
    union { unsigned u[4]; bf16x8 v; } pf0, pf1;
    pf0.u[0] = cvtpk(s[0][0], s[0][1]); pf0.u[1] = cvtpk(s[0][2], s[0][3]);
    pf0.u[2] = cvtpk(s[1][0], s[1][1]); pf0.u[3] = cvtpk(s[1][2], s[1][3]);
    pf1.u[0] = cvtpk(s[2][0], s[2][1]); pf1.u[1] = cvtpk(s[2][2], s[2][3]);
    pf1.u[2] = cvtpk(s[3][0], s[3][1]); pf1.u[3] = cvtpk(s[3][2], s[3][3]);
    int s0 = g >> 1, h8 = (g & 1) * 8;
    int vo0 = lr * 128 + h8 + (((s0 + 0) ^ l7) << 4);
    int vo1 = lr * 128 + h8 + (((s0 + 2) ^ l7) << 4);
    int vo2 = lr * 128 + h8 + (((s0 + 4) ^ l7) << 4);
    int vo3 = lr * 128 + h8 + (((s0 + 6) ^ l7) << 4);
#pragma unroll
    for (int nt = 0; nt < 4; ++nt) {
        union { uint2 u2[2]; bf16x8 v; } vf;
        vf.u2[0] = *(const uint2*)(vc + nt * 2048 + vo0);
        vf.u2[1] = *(const uint2*)(vc + nt * 2048 + vo1);
        y[nt] = MFMA16(vf.v, pf0.v, y[nt]);
        union { uint2 u2[2]; bf16x8 v; } vg;
        vg.u2[0] = *(const uint2*)(vc + nt * 2048 + vo2);
        vg.u2[1] = *(const uint2*)(vc + nt * 2048 + vo3);
        y[nt] = MFMA16(vg.v, pf1.v, y[nt]);
    }
}

__device__ __forceinline__ void attn_epilogue(unsigned short* smem, unsigned short* __restrict__ Yb,
                                              f32x4 (&y)[4], float rl, int qtile,
                                              int b, int hh, int w, int lr, int g, int tid) {
    __syncthreads();
    float inv = 1.0f / rl;
    char* ep = (char*)smem;
#pragma unroll
    for (int nt = 0; nt < 4; ++nt) {
        uint2 pr;
        pr.x = cvtpk(y[nt][0] * inv, y[nt][1] * inv);
        pr.y = cvtpk(y[nt][2] * inv, y[nt][3] * inv);
        *(uint2*)(ep + (w * 16 + lr) * 144 + (nt * 16 + g * 4) * 2) = pr;
    }
    __syncthreads();
    int q = tid >> 2, dc = (tid & 3) * 16;
    uint4 u0 = *(const uint4*)(ep + q * 144 + dc * 2);
    uint4 u1 = *(const uint4*)(ep + q * 144 + dc * 2 + 16);
    size_t orow = ((size_t)(b * 1024 + qtile * 64 + q)) * 1024 + hh * 64 + dc;
    *(uint4*)(Yb + orow) = u0;
    *(uint4*)(Yb + orow + 8) = u1;
}

__global__ __launch_bounds__(256) void attn_fwd(const unsigned short* __restrict__ Qh,
                                                const unsigned short* __restrict__ Kh,
                                                const unsigned short* __restrict__ Vt,
                                                unsigned short* __restrict__ Yb) {
    __shared__ __attribute__((aligned(16))) unsigned short smem[8192];
    unsigned short* Ks = smem;
    unsigned short* Vs = smem + 4096;

    int bid = blockIdx.x;
    int lg = (bid & 7) * 128 + (bid >> 3);
    int bh = lg >> 3, p = lg & 7;
    int qa = p, qb = 15 - p;

    int tid = threadIdx.x, w = tid >> 6, l = tid & 63;
    int lr = l & 15, g = l >> 4;
    int ldsb = __builtin_amdgcn_readfirstlane(w * 512);

    size_t bh64 = (size_t)bh * 65536;
    const unsigned short* qbase = Qh + bh64 + (size_t)(w * 16 + lr) * 64 + g * 8;
    bf16x8 qA0 = ld_bf16x8(qbase + qa * 4096);
    bf16x8 qA1 = ld_bf16x8(qbase + qa * 4096 + 32);
    bf16x8 qB0 = ld_bf16x8(qbase + qb * 4096);
    bf16x8 qB1 = ld_bf16x8(qbase + qb * 4096 + 32);

    f32x4 yA[4] = {}, yB[4] = {};
    float mA = -3e38f, lA = 0.f, mB = -3e38f, lB = 0.f;

    int c0 = tid, c1 = tid + 256;
    const unsigned short* K0 = Kh + bh64 + (c0 >> 3) * 64 + ((c0 ^ (c0 >> 3)) & 7) * 8;
    const unsigned short* K1 = Kh + bh64 + (c1 >> 3) * 64 + ((c1 ^ (c1 >> 3)) & 7) * 8;
    const unsigned short* V0 = Vt + bh64 + (c0 >> 3) * 1024 + ((c0 ^ (c0 >> 3)) & 7) * 8;
    const unsigned short* V1 = Vt + bh64 + (c1 >> 3) * 1024 + ((c1 ^ (c1 >> 3)) & 7) * 8;

    for (int t = 0; t <= qb; ++t) {
        __syncthreads();
        __builtin_amdgcn_global_load_lds((const as1_u32*)(K0 + t * 4096), (as3_u32*)(Ks + ldsb), 16, 0, 0);
        __builtin_amdgcn_global_load_lds((const as1_u32*)(K1 + t * 4096), (as3_u32*)(Ks + 2048 + ldsb), 16, 0, 0);
        __builtin_amdgcn_global_load_lds((const as1_u32*)(V0 + t * 64), (as3_u32*)(Vs + ldsb), 16, 0, 0);
        __builtin_amdgcn_global_load_lds((const as1_u32*)(V1 + t * 64), (as3_u32*)(Vs + 2048 + ldsb), 16, 0, 0);
        __syncthreads();

        if (t <= qa)
            attn_tile(Ks, Vs, qA0, qA1, yA, mA, lA, lr, g, t == qa, w * 16);
        attn_tile(Ks, Vs, qB0, qB1, yB, mB, lB, lr, g, t == qb, w * 16);
    }

    int b = bh >> 4, hh = bh & 15;
    attn_epilogue(smem, Yb, yA, lA, qa, b, hh, w, lr, g, tid);
    attn_epilogue(smem, Yb, yB, lB, qb, b, hh, w, lr, g, tid);
}

// ---------------------------------------------------------------------------
extern "C" void kernel_launch(void* const* d_in, const int* in_sizes, int n_in,
                              void* d_out, int out_size, void* d_ws, size_t ws_size,
                              hipStream_t stream) {
    const float* x = (const float*)d_in[0];
    const float* ipw = (const float*)d_in[1];
    const float* ipb = (const float*)d_in[2];
    const float* opw = (const float*)d_in[3];
    const float* opb = (const float*)d_in[4];

    char* ws = (char*)d_ws;
    unsigned short* xb   = (unsigned short*)(ws);               // 16 MB
    unsigned short* wqkv = (unsigned short*)(ws + 16777216);    // 6 MB
    unsigned short* wo   = (unsigned short*)(ws + 23068672);    // 2 MB
    float* ct            = (float*)(ws + 25165824);             // 128 KB
    float* st            = (float*)(ws + 25296896);             // 128 KB
    unsigned short* qkvb = (unsigned short*)(ws + 25427968);    // 48 MB
    unsigned short* Qh   = (unsigned short*)(ws + 75759616);    // 16 MB
    unsigned short* Kh   = (unsigned short*)(ws + 92536832);    // 16 MB
    unsigned short* Vt   = (unsigned short*)(ws + 109314048);   // 16 MB
    unsigned short* yb   = (unsigned short*)(ws + 126091264);   // 16 MB

    cast_f32_bf16<<<4096, 256, 0, stream>>>(x, xb, 1048576);
    cast_f32_bf16<<<1536, 256, 0, stream>>>(ipw, wqkv, 393216);
    cast_f32_bf16<<<512, 256, 0, stream>>>(opw, wo, 131072);
    rope_table<<<128, 256, 0, stream>>>(ct, st);

    gemm1_p<<<512, 512, 0, stream>>>(xb, wqkv, ipb, qkvb);
    rope_reshape<<<8192, 256, 0, stream>>>(qkvb, ct, st, Qh, Kh);
    transpose_v<<<2048, 256, 0, stream>>>(qkvb, Vt);
    attn_fwd<<<1024, 256, 0, stream>>>(Qh, Kh, Vt, yb);
    gemm2_p<<<256, 512, 0, stream>>>(yb, wo, opb, (float*)d_out);
}